// Round 3
// baseline (941.852 us; speedup 1.0000x reference)
//
#include <hip/hip_runtime.h>
#include <hip/hip_bf16.h>

// ---- problem constants (fixed by reference) ----
#define NN 50000
#define NE 800000
#define FIN 256
#define HEADS_H 3
#define HDIM 192
#define NEG_SLOPE 0.2f

typedef __attribute__((ext_vector_type(8))) short frag8;   // guide-verified MFMA operand type
typedef __attribute__((ext_vector_type(4))) float f32x4;
typedef unsigned short u16;

__device__ inline u16 f2b(float x) {
    __hip_bfloat16 h = __float2bfloat16(x);
    return __builtin_bit_cast(u16, h);
}
__device__ inline float b2f(u16 b) {
    __hip_bfloat16 h = __builtin_bit_cast(__hip_bfloat16, b);
    return __bfloat162float(h);
}

__device__ inline float wave_sum(float v) {
#pragma unroll
    for (int off = 32; off > 0; off >>= 1) v += __shfl_xor(v, off, 64);
    return v;
}
__device__ inline float wave_max(float v) {
#pragma unroll
    for (int off = 32; off > 0; off >>= 1) v = fmaxf(v, __shfl_xor(v, off, 64));
    return v;
}

// ---------------- diagnostics / utility ----------------
__global__ void k_fill_pattern(u16* __restrict__ p, int n, u16 v) {
    int i = blockIdx.x * blockDim.x + threadIdx.x;
    if (i < n) p[i] = v;
}
__global__ void k_zero(int* __restrict__ p, int n) {
    int i = blockIdx.x * blockDim.x + threadIdx.x;
    if (i < n) p[i] = 0;
}
__global__ void k_copy(const int* __restrict__ a, int* __restrict__ b, int n) {
    int i = blockIdx.x * blockDim.x + threadIdx.x;
    if (i < n) b[i] = a[i];
}

// dtype sniffer: fp32 N(0,1) data -> nearly all dwords decode to |x| in [1e-4,100].
// bf16-pair data -> fp32 exponent comes from bf16 mantissa bits -> almost never in range.
__global__ void k_sniff(const unsigned* __restrict__ p, int* __restrict__ flag) {
    __shared__ int cnt_s;
    if (threadIdx.x == 0) cnt_s = 0;
    __syncthreads();
    int c = 0;
    for (int i = threadIdx.x; i < 4096; i += 256) {
        float v = __builtin_bit_cast(float, p[i]);
        float a = fabsf(v);
        if (a > 1e-4f && a < 100.f) c++;
    }
    atomicAdd(&cnt_s, c);
    __syncthreads();
    if (threadIdx.x == 0) *flag = (cnt_s > 2048) ? 1 : 0;  // 1 = inputs are fp32
}

// convert small array to canonical bf16 (branch on runtime dtype flag)
__global__ void k_cvt_small(const void* __restrict__ in, u16* __restrict__ out, int n,
                            const int* __restrict__ flag) {
    int i = blockIdx.x * blockDim.x + threadIdx.x;
    if (i < n) {
        if (*flag) out[i] = f2b(((const float*)in)[i]);
        else out[i] = ((const u16*)in)[i];
    }
}

// BT[n*K+k] = cvt(B[k*N+n])
__global__ void k_transpose_cvt(const void* __restrict__ B, u16* __restrict__ BT, int K, int N,
                                const int* __restrict__ flag) {
    int i = blockIdx.x * blockDim.x + threadIdx.x;
    if (i < K * N) {
        int k = i / N, n = i - k * N;
        u16 v = (*flag) ? f2b(((const float*)B)[i]) : ((const u16*)B)[i];
        BT[n * K + k] = v;
    }
}

// ---------------- CSR build ----------------
__global__ void k_count(const int* __restrict__ dst, int* __restrict__ cnt, int E) {
    int e = blockIdx.x * blockDim.x + threadIdx.x;
    if (e < E) atomicAdd(&cnt[dst[e]], 1);
}

__global__ void k_scan(const int* __restrict__ cnt, int* __restrict__ indptr, int n) {
    __shared__ int sums[1024];
    int t = threadIdx.x;
    int CH = (n + 1023) >> 10;
    int s0 = t * CH, s1 = min(s0 + CH, n);
    int s = 0;
    for (int i = s0; i < s1; ++i) s += cnt[i];
    sums[t] = s;
    __syncthreads();
    for (int off = 1; off < 1024; off <<= 1) {
        int v = (t >= off) ? sums[t - off] : 0;
        __syncthreads();
        sums[t] += v;
        __syncthreads();
    }
    int excl = (t == 0) ? 0 : sums[t - 1];
    for (int i = s0; i < s1 && i < n; ++i) { indptr[i] = excl; excl += cnt[i]; }
    if (t == 1023) indptr[n] = sums[1023];
}

__global__ void k_fill(const int* __restrict__ dst, int* __restrict__ cursor,
                       int* __restrict__ eids, int E) {
    int e = blockIdx.x * blockDim.x + threadIdx.x;
    if (e < E) {
        int p = atomicAdd(&cursor[dst[e]], 1);
        eids[p] = e;
    }
}

// ---------------- MFMA GEMM: C[M,N] = A[M,K]*B[K,N], fp32 acc ----------------
// A: row-major, bf16 canonical OR (a_dual && *flag) fp32. BT: canonical bf16 [N,K].
// C: bf16, or (c_dual && *flag) fp32. One wave per 16 rows.
template <int NT>
__global__ __launch_bounds__(64) void k_gemm(const void* __restrict__ A, int a_dual,
                                             const u16* __restrict__ BT, void* __restrict__ C,
                                             int c_dual, const u16* __restrict__ bias,
                                             const int* __restrict__ flag, int M, int K,
                                             int relu) {
    const int lane = threadIdx.x;
    const int c16 = lane & 15;
    const int quad = lane >> 4;
    const int m_base = blockIdx.x * 16;
    int arow = m_base + c16;
    if (arow >= M) arow = M - 1;
    const int f = *flag;
    const bool a32 = a_dual && f;
    const bool c32 = c_dual && f;

    f32x4 acc[NT];
#pragma unroll
    for (int t = 0; t < NT; ++t) acc[t] = (f32x4)0.f;

    for (int k0 = 0; k0 < K; k0 += 32) {
        frag8 a;
        if (a32) {
            const float* ap = (const float*)A + (size_t)arow * K + k0 + quad * 8;
            f32x4 f0 = *(const f32x4*)ap;
            f32x4 f1 = *(const f32x4*)(ap + 4);
            a[0] = (short)f2b(f0[0]); a[1] = (short)f2b(f0[1]);
            a[2] = (short)f2b(f0[2]); a[3] = (short)f2b(f0[3]);
            a[4] = (short)f2b(f1[0]); a[5] = (short)f2b(f1[1]);
            a[6] = (short)f2b(f1[2]); a[7] = (short)f2b(f1[3]);
        } else {
            a = *(const frag8*)((const u16*)A + (size_t)arow * K + k0 + quad * 8);
        }
#pragma unroll
        for (int t = 0; t < NT; ++t) {
            frag8 b = *(const frag8*)(BT + (size_t)(t * 16 + c16) * K + k0 + quad * 8);
            acc[t] = __builtin_amdgcn_mfma_f32_16x16x32_bf16(a, b, acc[t], 0, 0, 0);
        }
    }

    const int N = NT * 16;
#pragma unroll
    for (int t = 0; t < NT; ++t) {
        int col = t * 16 + c16;
        float bv = bias ? b2f(bias[col]) : 0.f;
#pragma unroll
        for (int r = 0; r < 4; ++r) {
            int m = m_base + quad * 4 + r;
            if (m < M) {
                float v = acc[t][r] + bv;
                if (relu) v = fmaxf(v, 0.f);
                if (c32) ((float*)C)[(size_t)m * N + col] = v;
                else ((__hip_bfloat16*)C)[(size_t)m * N + col] = __float2bfloat16(v);
            }
        }
    }
}

// ---------------- el/er (feat: canonical bf16) ----------------
__global__ void k_el_er(const u16* __restrict__ feat, const u16* __restrict__ al,
                        const u16* __restrict__ ar, float* __restrict__ el,
                        float* __restrict__ er, int n_nodes) {
    int wave = threadIdx.x >> 6, lane = threadIdx.x & 63;
    int n = blockIdx.x * 4 + wave;
    if (n >= n_nodes) return;
#pragma unroll
    for (int h = 0; h < HEADS_H; ++h) {
        float fv = b2f(feat[(size_t)n * HDIM + h * 64 + lane]);
        float vl = fv * b2f(al[h * 64 + lane]);
        float vr = fv * b2f(ar[h * 64 + lane]);
        vl = wave_sum(vl);
        vr = wave_sum(vr);
        if (lane == 0) {
            el[n * HEADS_H + h] = vl;
            er[n * HEADS_H + h] = vr;
        }
    }
}

// ---------------- edge softmax per dst node ----------------
__global__ void k_softmax(const float* __restrict__ el, const float* __restrict__ er,
                          const int* __restrict__ src, const int* __restrict__ indptr,
                          const int* __restrict__ eids, float* __restrict__ alpha,
                          int n_nodes) {
    int wave = threadIdx.x >> 6, lane = threadIdx.x & 63;
    int n = blockIdx.x * 4 + wave;
    if (n >= n_nodes) return;
    int beg = indptr[n], end = indptr[n + 1];

    float er_h[HEADS_H];
#pragma unroll
    for (int h = 0; h < HEADS_H; ++h) er_h[h] = er[n * HEADS_H + h];

    float mh[HEADS_H];
#pragma unroll
    for (int h = 0; h < HEADS_H; ++h) mh[h] = -INFINITY;
    for (int i = beg + lane; i < end; i += 64) {
        int s = src[eids[i]];
#pragma unroll
        for (int h = 0; h < HEADS_H; ++h) {
            float ev = el[s * HEADS_H + h] + er_h[h];
            ev = (ev > 0.f) ? ev : NEG_SLOPE * ev;
            mh[h] = fmaxf(mh[h], ev);
        }
    }
#pragma unroll
    for (int h = 0; h < HEADS_H; ++h) mh[h] = wave_max(mh[h]);

    float sh[HEADS_H] = {0.f, 0.f, 0.f};
    for (int i = beg + lane; i < end; i += 64) {
        int e = eids[i];
        int s = src[e];
#pragma unroll
        for (int h = 0; h < HEADS_H; ++h) {
            float ev = el[s * HEADS_H + h] + er_h[h];
            ev = (ev > 0.f) ? ev : NEG_SLOPE * ev;
            float ex = __expf(ev - mh[h]);
            alpha[(size_t)e * HEADS_H + h] = ex;
            sh[h] += ex;
        }
    }
#pragma unroll
    for (int h = 0; h < HEADS_H; ++h) sh[h] = wave_sum(sh[h]);
    float inv[HEADS_H];
#pragma unroll
    for (int h = 0; h < HEADS_H; ++h) inv[h] = (sh[h] > 0.f) ? 1.f / sh[h] : 0.f;

    for (int i = beg + lane; i < end; i += 64) {
        int e = eids[i];
#pragma unroll
        for (int h = 0; h < HEADS_H; ++h) alpha[(size_t)e * HEADS_H + h] *= inv[h];
    }
}

// ---------------- aggregation: out = relu(sum alpha*feat[src] + b) ----------------
__global__ void k_agg(const u16* __restrict__ feat, const float* __restrict__ alpha,
                      const int* __restrict__ src, const int* __restrict__ indptr,
                      const int* __restrict__ eids, const u16* __restrict__ bias,
                      u16* __restrict__ outb, int n_nodes) {
    int n = blockIdx.x;
    int t = threadIdx.x;  // 0..191
    int h = t >> 6;
    int beg = indptr[n], end = indptr[n + 1];
    float acc = 0.f;
    for (int i = beg; i < end; ++i) {
        int e = eids[i];
        float a = alpha[(size_t)e * HEADS_H + h];
        int s = src[e];
        acc += a * b2f(feat[(size_t)s * HDIM + t]);
    }
    float v = acc + b2f(bias[t]);
    v = fmaxf(v, 0.f);
    outb[(size_t)n * HDIM + t] = f2b(v);
}

// ---------------- launch ----------------
extern "C" void kernel_launch(void* const* d_in, const int* in_sizes, int n_in,
                              void* d_out, int out_size, void* d_ws, size_t ws_size,
                              hipStream_t stream) {
    const void* features = d_in[0];
    const int* src = (const int*)d_in[1];
    const int* dst = (const int*)d_in[2];
    const void* W1 = d_in[3];
    const void* al1 = d_in[4];
    const void* ar1 = d_in[5];
    const void* b1 = d_in[6];
    const void* W2 = d_in[7];
    const void* al2 = d_in[8];
    const void* ar2 = d_in[9];
    const void* b2 = d_in[10];
    const void* Wm1 = d_in[11];
    const void* bm1 = d_in[12];
    const void* Wm2 = d_in[13];
    const void* bm2 = d_in[14];

    // ---- workspace layout ----
    char* ws = (char*)d_ws;
    size_t off = 0;
    auto alloc = [&](size_t bytes) -> void* {
        void* p = ws + off;
        off = (off + bytes + 255) & ~(size_t)255;
        return p;
    };
    int* flag = (int*)alloc(4);
    u16* featb = (u16*)alloc((size_t)NN * HDIM * 2);
    u16* xbf = (u16*)alloc((size_t)NN * HDIM * 2);
    u16* mlph = (u16*)alloc((size_t)NN * 64 * 2);
    float* alpha = (float*)alloc((size_t)NE * HEADS_H * 4);
    float* el = (float*)alloc((size_t)NN * HEADS_H * 4);
    float* er = (float*)alloc((size_t)NN * HEADS_H * 4);
    int* indptr = (int*)alloc((size_t)(NN + 1) * 4);
    int* cnt = (int*)alloc((size_t)NN * 4);
    int* eids = (int*)alloc((size_t)NE * 4);
    u16* W1T = (u16*)alloc((size_t)FIN * HDIM * 2);
    u16* W2T = (u16*)alloc((size_t)HDIM * HDIM * 2);
    u16* Wm1T = (u16*)alloc((size_t)HDIM * 64 * 2);
    u16* Wm2T = (u16*)alloc((size_t)64 * 64 * 2);
    u16* al1c = (u16*)alloc(HDIM * 2);
    u16* ar1c = (u16*)alloc(HDIM * 2);
    u16* b1c = (u16*)alloc(HDIM * 2);
    u16* al2c = (u16*)alloc(HDIM * 2);
    u16* ar2c = (u16*)alloc(HDIM * 2);
    u16* b2c = (u16*)alloc(HDIM * 2);
    u16* bm1c = (u16*)alloc(64 * 2);
    u16* bm2c = (u16*)alloc(64 * 2);

    if (ws_size < off) {
        // SENTINEL: workspace too small -> fill d_out with bf16(1.0) and bail.
        k_fill_pattern<<<(out_size + 255) / 256, 256, 0, stream>>>((u16*)d_out, out_size, 0x3F80);
        return;
    }

    // startup probe: 0.25-pattern (decodes ~0.25 as bf16 AND as fp32 pairs)
    k_fill_pattern<<<(out_size + 255) / 256, 256, 0, stream>>>((u16*)d_out, out_size, 0x3E80);

    // dtype sniff
    k_sniff<<<1, 256, 0, stream>>>((const unsigned*)features, flag);

    // canonical small arrays
    k_cvt_small<<<1, 256, 0, stream>>>(al1, al1c, HDIM, flag);
    k_cvt_small<<<1, 256, 0, stream>>>(ar1, ar1c, HDIM, flag);
    k_cvt_small<<<1, 256, 0, stream>>>(b1, b1c, HDIM, flag);
    k_cvt_small<<<1, 256, 0, stream>>>(al2, al2c, HDIM, flag);
    k_cvt_small<<<1, 256, 0, stream>>>(ar2, ar2c, HDIM, flag);
    k_cvt_small<<<1, 256, 0, stream>>>(b2, b2c, HDIM, flag);
    k_cvt_small<<<1, 256, 0, stream>>>(bm1, bm1c, 64, flag);
    k_cvt_small<<<1, 256, 0, stream>>>(bm2, bm2c, 64, flag);

    // transposed canonical weights
    k_transpose_cvt<<<(FIN * HDIM + 255) / 256, 256, 0, stream>>>(W1, W1T, FIN, HDIM, flag);
    k_transpose_cvt<<<(HDIM * HDIM + 255) / 256, 256, 0, stream>>>(W2, W2T, HDIM, HDIM, flag);
    k_transpose_cvt<<<(HDIM * 64 + 255) / 256, 256, 0, stream>>>(Wm1, Wm1T, HDIM, 64, flag);
    k_transpose_cvt<<<(64 * 64 + 255) / 256, 256, 0, stream>>>(Wm2, Wm2T, 64, 64, flag);

    // CSR by dst
    k_zero<<<(NN + 255) / 256, 256, 0, stream>>>(cnt, NN);
    k_count<<<(NE + 255) / 256, 256, 0, stream>>>(dst, cnt, NE);
    k_scan<<<1, 1024, 0, stream>>>(cnt, indptr, NN);
    k_copy<<<(NN + 255) / 256, 256, 0, stream>>>(indptr, cnt, NN);
    k_fill<<<(NE + 255) / 256, 256, 0, stream>>>(dst, cnt, eids, NE);

    const int gemm_grid = (NN + 15) / 16;

    // GAT layer 1 (A = raw features, dual-dtype)
    k_gemm<12><<<gemm_grid, 64, 0, stream>>>(features, 1, W1T, featb, 0, nullptr, flag, NN, FIN, 0);
    k_el_er<<<(NN + 3) / 4, 256, 0, stream>>>(featb, al1c, ar1c, el, er, NN);
    k_softmax<<<(NN + 3) / 4, 256, 0, stream>>>(el, er, src, indptr, eids, alpha, NN);
    k_agg<<<NN, HDIM, 0, stream>>>(featb, alpha, src, indptr, eids, b1c, xbf, NN);

    // GAT layer 2
    k_gemm<12><<<gemm_grid, 64, 0, stream>>>(xbf, 0, W2T, featb, 0, nullptr, flag, NN, HDIM, 0);
    k_el_er<<<(NN + 3) / 4, 256, 0, stream>>>(featb, al2c, ar2c, el, er, NN);
    k_softmax<<<(NN + 3) / 4, 256, 0, stream>>>(el, er, src, indptr, eids, alpha, NN);
    k_agg<<<NN, HDIM, 0, stream>>>(featb, alpha, src, indptr, eids, b2c, xbf, NN);

    // MLP
    k_gemm<4><<<gemm_grid, 64, 0, stream>>>(xbf, 0, Wm1T, mlph, 0, bm1c, flag, NN, HDIM, 1);
    k_gemm<4><<<gemm_grid, 64, 0, stream>>>(mlph, 0, Wm2T, d_out, 1, bm2c, flag, NN, 64, 0);
}

// Round 4
// 654.014 us; speedup vs baseline: 1.4401x; 1.4401x over previous
//
#include <hip/hip_runtime.h>
#include <hip/hip_bf16.h>

// ---- problem constants (fixed by reference) ----
#define NN 50000
#define NE 800000
#define FIN 256
#define HEADS_H 3
#define HDIM 192
#define NEG_SLOPE 0.2f
#define CHUNK 128  // edges staged in LDS per iteration in k_agg

typedef __attribute__((ext_vector_type(8))) short frag8;
typedef __attribute__((ext_vector_type(4))) float f32x4;
typedef unsigned short u16;

__device__ inline u16 f2b(float x) {
    __hip_bfloat16 h = __float2bfloat16(x);
    return __builtin_bit_cast(u16, h);
}
__device__ inline float b2f(u16 b) {
    __hip_bfloat16 h = __builtin_bit_cast(__hip_bfloat16, b);
    return __bfloat162float(h);
}

__device__ inline float wave_sum(float v) {
#pragma unroll
    for (int off = 32; off > 0; off >>= 1) v += __shfl_xor(v, off, 64);
    return v;
}
__device__ inline float wave_max(float v) {
#pragma unroll
    for (int off = 32; off > 0; off >>= 1) v = fmaxf(v, __shfl_xor(v, off, 64));
    return v;
}

// ---------------- utility ----------------
__global__ void k_fill_pattern(u16* __restrict__ p, int n, u16 v) {
    int i = blockIdx.x * blockDim.x + threadIdx.x;
    if (i < n) p[i] = v;
}
__global__ void k_zero(int* __restrict__ p, int n) {
    int i = blockIdx.x * blockDim.x + threadIdx.x;
    if (i < n) p[i] = 0;
}

// dtype sniffer: fp32 N(0,1) data -> nearly all dwords decode to |x| in [1e-4,100].
__global__ void k_sniff(const unsigned* __restrict__ p, int* __restrict__ flag) {
    __shared__ int cnt_s;
    if (threadIdx.x == 0) cnt_s = 0;
    __syncthreads();
    int c = 0;
    for (int i = threadIdx.x; i < 4096; i += 256) {
        float v = __builtin_bit_cast(float, p[i]);
        float a = fabsf(v);
        if (a > 1e-4f && a < 100.f) c++;
    }
    atomicAdd(&cnt_s, c);
    __syncthreads();
    if (threadIdx.x == 0) *flag = (cnt_s > 2048) ? 1 : 0;  // 1 = inputs are fp32
}

// fuse all 8 small-array conversions into one dispatch (block b -> array b)
__global__ void k_cvt8(const void* i0, const void* i1, const void* i2, const void* i3,
                       const void* i4, const void* i5, const void* i6, const void* i7,
                       u16* o0, u16* o1, u16* o2, u16* o3, u16* o4, u16* o5, u16* o6, u16* o7,
                       const int* __restrict__ flag) {
    const void* ins[8] = {i0, i1, i2, i3, i4, i5, i6, i7};
    u16* outs[8] = {o0, o1, o2, o3, o4, o5, o6, o7};
    const int ns[8] = {HDIM, HDIM, HDIM, HDIM, HDIM, HDIM, 64, 64};
    int b = blockIdx.x;
    int n = ns[b];
    const void* in = ins[b];
    u16* out = outs[b];
    int f = *flag;
    for (int i = threadIdx.x; i < n; i += 256) {
        out[i] = f ? f2b(((const float*)in)[i]) : ((const u16*)in)[i];
    }
}

// BT[n*K+k] = cvt(B[k*N+n])
__global__ void k_transpose_cvt(const void* __restrict__ B, u16* __restrict__ BT, int K, int N,
                                const int* __restrict__ flag) {
    int i = blockIdx.x * blockDim.x + threadIdx.x;
    if (i < K * N) {
        int k = i / N, n = i - k * N;
        u16 v = (*flag) ? f2b(((const float*)B)[i]) : ((const u16*)B)[i];
        BT[n * K + k] = v;
    }
}

// ---------------- CSR build ----------------
__global__ void k_count(const int* __restrict__ dst, int* __restrict__ cnt, int E) {
    int e = blockIdx.x * blockDim.x + threadIdx.x;
    if (e < E) atomicAdd(&cnt[dst[e]], 1);
}

// scan cnt -> indptr; also re-init cnt as the fill cursor
__global__ void k_scan(int* __restrict__ cnt, int* __restrict__ indptr, int n) {
    __shared__ int sums[1024];
    int t = threadIdx.x;
    int CH = (n + 1023) >> 10;
    int s0 = t * CH, s1 = min(s0 + CH, n);
    int s = 0;
    for (int i = s0; i < s1; ++i) s += cnt[i];
    sums[t] = s;
    __syncthreads();
    for (int off = 1; off < 1024; off <<= 1) {
        int v = (t >= off) ? sums[t - off] : 0;
        __syncthreads();
        sums[t] += v;
        __syncthreads();
    }
    int excl = (t == 0) ? 0 : sums[t - 1];
    for (int i = s0; i < s1 && i < n; ++i) {
        indptr[i] = excl;
        int c = cnt[i];
        cnt[i] = excl;  // cursor init
        excl += c;
    }
    if (t == 1023) indptr[n] = sums[1023];
}

__global__ void k_fill(const int* __restrict__ dst, int* __restrict__ cursor,
                       int* __restrict__ eids, int E) {
    int e = blockIdx.x * blockDim.x + threadIdx.x;
    if (e < E) {
        int p = atomicAdd(&cursor[dst[e]], 1);
        eids[p] = e;
    }
}

// ---------------- MFMA GEMM: C[M,N] = A[M,K]*B[K,N], fp32 acc ----------------
// RT row-tiles of 16 per wave; B fragments shared across row tiles.
template <int NT, int RT>
__global__ __launch_bounds__(64) void k_gemm(const void* __restrict__ A, int a_dual,
                                             const u16* __restrict__ BT, void* __restrict__ C,
                                             int c_dual, const u16* __restrict__ bias,
                                             const int* __restrict__ flag, int M, int K,
                                             int relu) {
    const int lane = threadIdx.x;
    const int c16 = lane & 15;
    const int quad = lane >> 4;
    const int m_base = blockIdx.x * (16 * RT);
    const int f = *flag;
    const bool a32 = a_dual && f;
    const bool c32 = c_dual && f;

    int arow[RT];
#pragma unroll
    for (int r = 0; r < RT; ++r) {
        int m = m_base + r * 16 + c16;
        arow[r] = (m < M) ? m : (M - 1);
    }

    f32x4 acc[RT][NT];
#pragma unroll
    for (int r = 0; r < RT; ++r)
#pragma unroll
        for (int t = 0; t < NT; ++t) acc[r][t] = (f32x4)0.f;

    for (int k0 = 0; k0 < K; k0 += 32) {
        frag8 a[RT];
#pragma unroll
        for (int r = 0; r < RT; ++r) {
            if (a32) {
                const float* ap = (const float*)A + (size_t)arow[r] * K + k0 + quad * 8;
                f32x4 f0 = *(const f32x4*)ap;
                f32x4 f1 = *(const f32x4*)(ap + 4);
                a[r][0] = (short)f2b(f0[0]); a[r][1] = (short)f2b(f0[1]);
                a[r][2] = (short)f2b(f0[2]); a[r][3] = (short)f2b(f0[3]);
                a[r][4] = (short)f2b(f1[0]); a[r][5] = (short)f2b(f1[1]);
                a[r][6] = (short)f2b(f1[2]); a[r][7] = (short)f2b(f1[3]);
            } else {
                a[r] = *(const frag8*)((const u16*)A + (size_t)arow[r] * K + k0 + quad * 8);
            }
        }
#pragma unroll
        for (int t = 0; t < NT; ++t) {
            frag8 b = *(const frag8*)(BT + (size_t)(t * 16 + c16) * K + k0 + quad * 8);
#pragma unroll
            for (int r = 0; r < RT; ++r)
                acc[r][t] = __builtin_amdgcn_mfma_f32_16x16x32_bf16(a[r], b, acc[r][t], 0, 0, 0);
        }
    }

    const int N = NT * 16;
#pragma unroll
    for (int t = 0; t < NT; ++t) {
        int col = t * 16 + c16;
        float bv = bias ? b2f(bias[col]) : 0.f;
#pragma unroll
        for (int r = 0; r < RT; ++r) {
#pragma unroll
            for (int rr = 0; rr < 4; ++rr) {
                int m = m_base + r * 16 + quad * 4 + rr;
                if (m < M) {
                    float v = acc[r][t][rr] + bv;
                    if (relu) v = fmaxf(v, 0.f);
                    if (c32) ((float*)C)[(size_t)m * N + col] = v;
                    else ((__hip_bfloat16*)C)[(size_t)m * N + col] = __float2bfloat16(v);
                }
            }
        }
    }
}

// ---------------- el/er (feat: canonical bf16) ----------------
__global__ void k_el_er(const u16* __restrict__ feat, const u16* __restrict__ al,
                        const u16* __restrict__ ar, float* __restrict__ el,
                        float* __restrict__ er, int n_nodes) {
    int wave = threadIdx.x >> 6, lane = threadIdx.x & 63;
    int n = blockIdx.x * 4 + wave;
    if (n >= n_nodes) return;
#pragma unroll
    for (int h = 0; h < HEADS_H; ++h) {
        float fv = b2f(feat[(size_t)n * HDIM + h * 64 + lane]);
        float vl = fv * b2f(al[h * 64 + lane]);
        float vr = fv * b2f(ar[h * 64 + lane]);
        vl = wave_sum(vl);
        vr = wave_sum(vr);
        if (lane == 0) {
            el[n * HEADS_H + h] = vl;
            er[n * HEADS_H + h] = vr;
        }
    }
}

// ---------------- edge softmax per dst node ----------------
// Emits CSR-ordered src_perm[i], UNNORMALIZED exp in alpha_perm[i*3+h],
// and per-node inv_s[n*3+h]. Normalization is folded into k_agg.
__global__ void k_softmax(const float* __restrict__ el, const float* __restrict__ er,
                          const int* __restrict__ src, const int* __restrict__ indptr,
                          const int* __restrict__ eids, float* __restrict__ alpha_perm,
                          int* __restrict__ src_perm, float* __restrict__ inv_s, int n_nodes) {
    int wave = threadIdx.x >> 6, lane = threadIdx.x & 63;
    int n = blockIdx.x * 4 + wave;
    if (n >= n_nodes) return;
    int beg = indptr[n], end = indptr[n + 1];

    float er_h[HEADS_H];
#pragma unroll
    for (int h = 0; h < HEADS_H; ++h) er_h[h] = er[n * HEADS_H + h];

    float mh[HEADS_H];
#pragma unroll
    for (int h = 0; h < HEADS_H; ++h) mh[h] = -INFINITY;
    for (int i = beg + lane; i < end; i += 64) {
        int s = src[eids[i]];
        src_perm[i] = s;
#pragma unroll
        for (int h = 0; h < HEADS_H; ++h) {
            float ev = el[s * HEADS_H + h] + er_h[h];
            ev = (ev > 0.f) ? ev : NEG_SLOPE * ev;
            mh[h] = fmaxf(mh[h], ev);
        }
    }
#pragma unroll
    for (int h = 0; h < HEADS_H; ++h) mh[h] = wave_max(mh[h]);

    float sh[HEADS_H] = {0.f, 0.f, 0.f};
    for (int i = beg + lane; i < end; i += 64) {
        int s = src_perm[i];  // contiguous reload
#pragma unroll
        for (int h = 0; h < HEADS_H; ++h) {
            float ev = el[s * HEADS_H + h] + er_h[h];
            ev = (ev > 0.f) ? ev : NEG_SLOPE * ev;
            float ex = __expf(ev - mh[h]);
            alpha_perm[(size_t)i * HEADS_H + h] = ex;
            sh[h] += ex;
        }
    }
#pragma unroll
    for (int h = 0; h < HEADS_H; ++h) {
        sh[h] = wave_sum(sh[h]);
        if (lane == 0) inv_s[n * HEADS_H + h] = (sh[h] > 0.f) ? 1.f / sh[h] : 0.f;
    }
}

// ---------------- aggregation: out = relu(inv_s * sum(ex*feat[src]) + b) ----------------
// Block = 192 threads (one node), t -> dim. h = t>>6 is wave-uniform -> LDS broadcasts.
__global__ void k_agg(const u16* __restrict__ feat, const float* __restrict__ alpha_perm,
                      const int* __restrict__ src_perm, const int* __restrict__ indptr,
                      const float* __restrict__ inv_s, const u16* __restrict__ bias,
                      u16* __restrict__ outb, int n_nodes) {
    __shared__ int ssrc[CHUNK];
    __shared__ float salpha[CHUNK * HEADS_H];
    int n = blockIdx.x;
    int t = threadIdx.x;  // 0..191
    int h = t >> 6;
    int beg = indptr[n], end = indptr[n + 1];
    float acc = 0.f;

    for (int c0 = beg; c0 < end; c0 += CHUNK) {
        int len = min(CHUNK, end - c0);
        __syncthreads();
        for (int j = t; j < len; j += HDIM) ssrc[j] = src_perm[c0 + j];
        for (int j = t; j < HEADS_H * len; j += HDIM)
            salpha[j] = alpha_perm[(size_t)c0 * HEADS_H + j];
        __syncthreads();

        int j = 0;
        for (; j + 4 <= len; j += 4) {
            int s0 = ssrc[j], s1 = ssrc[j + 1], s2 = ssrc[j + 2], s3 = ssrc[j + 3];
            float f0 = b2f(feat[(size_t)s0 * HDIM + t]);
            float f1 = b2f(feat[(size_t)s1 * HDIM + t]);
            float f2 = b2f(feat[(size_t)s2 * HDIM + t]);
            float f3 = b2f(feat[(size_t)s3 * HDIM + t]);
            acc += salpha[j * HEADS_H + h] * f0;
            acc += salpha[(j + 1) * HEADS_H + h] * f1;
            acc += salpha[(j + 2) * HEADS_H + h] * f2;
            acc += salpha[(j + 3) * HEADS_H + h] * f3;
        }
        for (; j < len; ++j)
            acc += salpha[j * HEADS_H + h] * b2f(feat[(size_t)ssrc[j] * HDIM + t]);
    }

    float v = acc * inv_s[n * HEADS_H + h] + b2f(bias[t]);
    v = fmaxf(v, 0.f);
    outb[(size_t)n * HDIM + t] = f2b(v);
}

// ---------------- launch ----------------
extern "C" void kernel_launch(void* const* d_in, const int* in_sizes, int n_in,
                              void* d_out, int out_size, void* d_ws, size_t ws_size,
                              hipStream_t stream) {
    const void* features = d_in[0];
    const int* src = (const int*)d_in[1];
    const int* dst = (const int*)d_in[2];
    const void* W1 = d_in[3];
    const void* al1 = d_in[4];
    const void* ar1 = d_in[5];
    const void* b1 = d_in[6];
    const void* W2 = d_in[7];
    const void* al2 = d_in[8];
    const void* ar2 = d_in[9];
    const void* b2 = d_in[10];
    const void* Wm1 = d_in[11];
    const void* bm1 = d_in[12];
    const void* Wm2 = d_in[13];
    const void* bm2 = d_in[14];

    char* ws = (char*)d_ws;
    size_t off = 0;
    auto alloc = [&](size_t bytes) -> void* {
        void* p = ws + off;
        off = (off + bytes + 255) & ~(size_t)255;
        return p;
    };
    int* flag = (int*)alloc(4);
    u16* featb = (u16*)alloc((size_t)NN * HDIM * 2);
    u16* xbf = (u16*)alloc((size_t)NN * HDIM * 2);
    u16* mlph = (u16*)alloc((size_t)NN * 64 * 2);
    float* alpha_perm = (float*)alloc((size_t)NE * HEADS_H * 4);
    float* el = (float*)alloc((size_t)NN * HEADS_H * 4);
    float* er = (float*)alloc((size_t)NN * HEADS_H * 4);
    float* inv_s = (float*)alloc((size_t)NN * HEADS_H * 4);
    int* indptr = (int*)alloc((size_t)(NN + 1) * 4);
    int* cnt = (int*)alloc((size_t)NN * 4);
    int* eids = (int*)alloc((size_t)NE * 4);
    int* src_perm = (int*)alloc((size_t)NE * 4);
    u16* W1T = (u16*)alloc((size_t)FIN * HDIM * 2);
    u16* W2T = (u16*)alloc((size_t)HDIM * HDIM * 2);
    u16* Wm1T = (u16*)alloc((size_t)HDIM * 64 * 2);
    u16* Wm2T = (u16*)alloc((size_t)64 * 64 * 2);
    u16* al1c = (u16*)alloc(HDIM * 2);
    u16* ar1c = (u16*)alloc(HDIM * 2);
    u16* b1c = (u16*)alloc(HDIM * 2);
    u16* al2c = (u16*)alloc(HDIM * 2);
    u16* ar2c = (u16*)alloc(HDIM * 2);
    u16* b2c = (u16*)alloc(HDIM * 2);
    u16* bm1c = (u16*)alloc(64 * 2);
    u16* bm2c = (u16*)alloc(64 * 2);

    if (ws_size < off) {
        k_fill_pattern<<<(out_size + 255) / 256, 256, 0, stream>>>((u16*)d_out, out_size, 0x3F80);
        return;
    }

    k_sniff<<<1, 256, 0, stream>>>((const unsigned*)features, flag);

    k_cvt8<<<8, 256, 0, stream>>>(al1, ar1, b1, al2, ar2, b2, bm1, bm2, al1c, ar1c, b1c, al2c,
                                  ar2c, b2c, bm1c, bm2c, flag);

    k_transpose_cvt<<<(FIN * HDIM + 255) / 256, 256, 0, stream>>>(W1, W1T, FIN, HDIM, flag);
    k_transpose_cvt<<<(HDIM * HDIM + 255) / 256, 256, 0, stream>>>(W2, W2T, HDIM, HDIM, flag);
    k_transpose_cvt<<<(HDIM * 64 + 255) / 256, 256, 0, stream>>>(Wm1, Wm1T, HDIM, 64, flag);
    k_transpose_cvt<<<(64 * 64 + 255) / 256, 256, 0, stream>>>(Wm2, Wm2T, 64, 64, flag);

    k_zero<<<(NN + 255) / 256, 256, 0, stream>>>(cnt, NN);
    k_count<<<(NE + 255) / 256, 256, 0, stream>>>(dst, cnt, NE);
    k_scan<<<1, 1024, 0, stream>>>(cnt, indptr, NN);
    k_fill<<<(NE + 255) / 256, 256, 0, stream>>>(dst, cnt, eids, NE);

    const int g32 = (NN + 31) / 32;  // RT=2 grid

    // GAT layer 1
    k_gemm<12, 2><<<g32, 64, 0, stream>>>(features, 1, W1T, featb, 0, nullptr, flag, NN, FIN, 0);
    k_el_er<<<(NN + 3) / 4, 256, 0, stream>>>(featb, al1c, ar1c, el, er, NN);
    k_softmax<<<(NN + 3) / 4, 256, 0, stream>>>(el, er, src, indptr, eids, alpha_perm, src_perm,
                                                inv_s, NN);
    k_agg<<<NN, HDIM, 0, stream>>>(featb, alpha_perm, src_perm, indptr, inv_s, b1c, xbf, NN);

    // GAT layer 2
    k_gemm<12, 2><<<g32, 64, 0, stream>>>(xbf, 0, W2T, featb, 0, nullptr, flag, NN, HDIM, 0);
    k_el_er<<<(NN + 3) / 4, 256, 0, stream>>>(featb, al2c, ar2c, el, er, NN);
    k_softmax<<<(NN + 3) / 4, 256, 0, stream>>>(el, er, src, indptr, eids, alpha_perm, src_perm,
                                                inv_s, NN);
    k_agg<<<NN, HDIM, 0, stream>>>(featb, alpha_perm, src_perm, indptr, inv_s, b2c, xbf, NN);

    // MLP
    k_gemm<4, 2><<<g32, 64, 0, stream>>>(xbf, 0, Wm1T, mlph, 0, bm1c, flag, NN, HDIM, 1);
    k_gemm<4, 2><<<g32, 64, 0, stream>>>(mlph, 0, Wm2T, d_out, 1, bm2c, flag, NN, 64, 0);
}

// Round 5
// 553.334 us; speedup vs baseline: 1.7021x; 1.1820x over previous
//
#include <hip/hip_runtime.h>
#include <hip/hip_bf16.h>

// ---- problem constants (fixed by reference) ----
#define NN 50000
#define NE 800000
#define FIN 256
#define HEADS_H 3
#define HDIM 192
#define NEG_SLOPE 0.2f
#define CHUNK 128        // edges staged in LDS per iteration in k_agg
#define SCAN_ELEMS 512   // elements per scan block
#define SCAN_NB ((NN + SCAN_ELEMS - 1) / SCAN_ELEMS)  // 98

typedef __attribute__((ext_vector_type(8))) short frag8;
typedef __attribute__((ext_vector_type(4))) float f32x4;
typedef unsigned short u16;

__device__ inline u16 f2b(float x) {
    __hip_bfloat16 h = __float2bfloat16(x);
    return __builtin_bit_cast(u16, h);
}
__device__ inline float b2f(u16 b) {
    __hip_bfloat16 h = __builtin_bit_cast(__hip_bfloat16, b);
    return __bfloat162float(h);
}

__device__ inline float wave_sum(float v) {
#pragma unroll
    for (int off = 32; off > 0; off >>= 1) v += __shfl_xor(v, off, 64);
    return v;
}
__device__ inline int wave_sum_i(int v) {
#pragma unroll
    for (int off = 32; off > 0; off >>= 1) v += __shfl_xor(v, off, 64);
    return v;
}
__device__ inline float wave_max(float v) {
#pragma unroll
    for (int off = 32; off > 0; off >>= 1) v = fmaxf(v, __shfl_xor(v, off, 64));
    return v;
}

// ---------------- utility ----------------
__global__ void k_fill_pattern(u16* __restrict__ p, int n, u16 v) {
    int i = blockIdx.x * blockDim.x + threadIdx.x;
    if (i < n) p[i] = v;
}
__global__ void k_zero(int* __restrict__ p, int n) {
    int i = blockIdx.x * blockDim.x + threadIdx.x;
    if (i < n) p[i] = 0;
}

// dtype sniffer: fp32 N(0,1) data -> nearly all dwords decode to |x| in [1e-4,100].
__global__ void k_sniff(const unsigned* __restrict__ p, int* __restrict__ flag) {
    __shared__ int cnt_s;
    if (threadIdx.x == 0) cnt_s = 0;
    __syncthreads();
    int c = 0;
    for (int i = threadIdx.x; i < 4096; i += 256) {
        float v = __builtin_bit_cast(float, p[i]);
        float a = fabsf(v);
        if (a > 1e-4f && a < 100.f) c++;
    }
    atomicAdd(&cnt_s, c);
    __syncthreads();
    if (threadIdx.x == 0) *flag = (cnt_s > 2048) ? 1 : 0;  // 1 = inputs are fp32
}

// fuse all 8 small-array conversions into one dispatch (block b -> array b)
__global__ void k_cvt8(const void* i0, const void* i1, const void* i2, const void* i3,
                       const void* i4, const void* i5, const void* i6, const void* i7,
                       u16* o0, u16* o1, u16* o2, u16* o3, u16* o4, u16* o5, u16* o6, u16* o7,
                       const int* __restrict__ flag) {
    const void* ins[8] = {i0, i1, i2, i3, i4, i5, i6, i7};
    u16* outs[8] = {o0, o1, o2, o3, o4, o5, o6, o7};
    const int ns[8] = {HDIM, HDIM, HDIM, HDIM, HDIM, HDIM, 64, 64};
    int b = blockIdx.x;
    int n = ns[b];
    const void* in = ins[b];
    u16* out = outs[b];
    int f = *flag;
    for (int i = threadIdx.x; i < n; i += 256) {
        out[i] = f ? f2b(((const float*)in)[i]) : ((const u16*)in)[i];
    }
}

// all 4 weight transposes in ONE dispatch: T[n*K+k] = cvt(B[k*N+n])
__global__ void k_transpose4(const void* __restrict__ B0, const void* __restrict__ B1,
                             const void* __restrict__ B2, const void* __restrict__ B3,
                             u16* __restrict__ T0, u16* __restrict__ T1, u16* __restrict__ T2,
                             u16* __restrict__ T3, const int* __restrict__ flag) {
    const int n0 = FIN * HDIM, n1 = HDIM * HDIM, n2 = HDIM * 64, n3 = 64 * 64;
    int gi = blockIdx.x * 256 + threadIdx.x;
    const void* B;
    u16* T;
    int K, N, i;
    if (gi < n0) { B = B0; T = T0; K = FIN; N = HDIM; i = gi; }
    else if (gi < n0 + n1) { B = B1; T = T1; K = HDIM; N = HDIM; i = gi - n0; }
    else if (gi < n0 + n1 + n2) { B = B2; T = T2; K = HDIM; N = 64; i = gi - n0 - n1; }
    else if (gi < n0 + n1 + n2 + n3) { B = B3; T = T3; K = 64; N = 64; i = gi - n0 - n1 - n2; }
    else return;
    int k = i / N, n = i - k * N;
    u16 v = (*flag) ? f2b(((const float*)B)[i]) : ((const u16*)B)[i];
    T[n * K + k] = v;
}

// ---------------- CSR build ----------------
__global__ void k_count(const int* __restrict__ dst, int* __restrict__ cnt, int E) {
    int e = blockIdx.x * blockDim.x + threadIdx.x;
    if (e < E) atomicAdd(&cnt[dst[e]], 1);
}

// phase 1: per-block partial sums (256 threads, 2 elems/thread)
__global__ void k_scan_partial(const int* __restrict__ cnt, int* __restrict__ partial) {
    int b = blockIdx.x, t = threadIdx.x;
    int i0 = b * SCAN_ELEMS + t * 2;
    int v = 0;
    if (i0 < NN) v += cnt[i0];
    if (i0 + 1 < NN) v += cnt[i0 + 1];
    v = wave_sum_i(v);
    __shared__ int wsum[4];
    if ((t & 63) == 0) wsum[t >> 6] = v;
    __syncthreads();
    if (t == 0) partial[b] = wsum[0] + wsum[1] + wsum[2] + wsum[3];
}

// phase 2: single small block scans SCAN_NB partials -> block offsets; total -> indptr[NN]
__global__ void k_scan_mid(const int* __restrict__ partial, int* __restrict__ offsets,
                           int* __restrict__ indptr) {
    __shared__ int s[SCAN_NB];
    int t = threadIdx.x;  // 128 >= SCAN_NB
    if (t < SCAN_NB) s[t] = partial[t];
    __syncthreads();
    for (int off = 1; off < SCAN_NB; off <<= 1) {
        int v = (t >= off && t < SCAN_NB) ? s[t - off] : 0;
        __syncthreads();
        if (t < SCAN_NB) s[t] += v;
        __syncthreads();
    }
    if (t < SCAN_NB) offsets[t] = (t == 0) ? 0 : s[t - 1];
    if (t == 0) indptr[NN] = s[SCAN_NB - 1];
}

// phase 3: intra-block exclusive scan + offset; writes indptr and cursor (cnt)
__global__ void k_scan_final(int* __restrict__ cnt, const int* __restrict__ offsets,
                             int* __restrict__ indptr) {
    __shared__ int tsum[256];
    int b = blockIdx.x, t = threadIdx.x;
    int i0 = b * SCAN_ELEMS + t * 2;
    int c0 = (i0 < NN) ? cnt[i0] : 0;
    int c1 = (i0 + 1 < NN) ? cnt[i0 + 1] : 0;
    tsum[t] = c0 + c1;
    __syncthreads();
    for (int off = 1; off < 256; off <<= 1) {
        int v = (t >= off) ? tsum[t - off] : 0;
        __syncthreads();
        tsum[t] += v;
        __syncthreads();
    }
    int excl = offsets[b] + ((t == 0) ? 0 : tsum[t - 1]);
    if (i0 < NN) { indptr[i0] = excl; cnt[i0] = excl; }
    if (i0 + 1 < NN) { indptr[i0 + 1] = excl + c0; cnt[i0 + 1] = excl + c0; }
}

__global__ void k_fill(const int* __restrict__ dst, int* __restrict__ cursor,
                       int* __restrict__ eids, int E) {
    int e = blockIdx.x * blockDim.x + threadIdx.x;
    if (e < E) {
        int p = atomicAdd(&cursor[dst[e]], 1);
        eids[p] = e;
    }
}

// ---------------- MFMA GEMM: C[M,N] = A[M,K]*B[K,N], fp32 acc ----------------
template <int NT, int RT>
__global__ __launch_bounds__(64) void k_gemm(const void* __restrict__ A, int a_dual,
                                             const u16* __restrict__ BT, void* __restrict__ C,
                                             int c_dual, const u16* __restrict__ bias,
                                             const int* __restrict__ flag, int M, int K,
                                             int relu) {
    const int lane = threadIdx.x;
    const int c16 = lane & 15;
    const int quad = lane >> 4;
    const int m_base = blockIdx.x * (16 * RT);
    const int f = *flag;
    const bool a32 = a_dual && f;
    const bool c32 = c_dual && f;

    int arow[RT];
#pragma unroll
    for (int r = 0; r < RT; ++r) {
        int m = m_base + r * 16 + c16;
        arow[r] = (m < M) ? m : (M - 1);
    }

    f32x4 acc[RT][NT];
#pragma unroll
    for (int r = 0; r < RT; ++r)
#pragma unroll
        for (int t = 0; t < NT; ++t) acc[r][t] = (f32x4)0.f;

    for (int k0 = 0; k0 < K; k0 += 32) {
        frag8 a[RT];
#pragma unroll
        for (int r = 0; r < RT; ++r) {
            if (a32) {
                const float* ap = (const float*)A + (size_t)arow[r] * K + k0 + quad * 8;
                f32x4 f0 = *(const f32x4*)ap;
                f32x4 f1 = *(const f32x4*)(ap + 4);
                a[r][0] = (short)f2b(f0[0]); a[r][1] = (short)f2b(f0[1]);
                a[r][2] = (short)f2b(f0[2]); a[r][3] = (short)f2b(f0[3]);
                a[r][4] = (short)f2b(f1[0]); a[r][5] = (short)f2b(f1[1]);
                a[r][6] = (short)f2b(f1[2]); a[r][7] = (short)f2b(f1[3]);
            } else {
                a[r] = *(const frag8*)((const u16*)A + (size_t)arow[r] * K + k0 + quad * 8);
            }
        }
#pragma unroll
        for (int t = 0; t < NT; ++t) {
            frag8 b = *(const frag8*)(BT + (size_t)(t * 16 + c16) * K + k0 + quad * 8);
#pragma unroll
            for (int r = 0; r < RT; ++r)
                acc[r][t] = __builtin_amdgcn_mfma_f32_16x16x32_bf16(a[r], b, acc[r][t], 0, 0, 0);
        }
    }

    const int N = NT * 16;
#pragma unroll
    for (int t = 0; t < NT; ++t) {
        int col = t * 16 + c16;
        float bv = bias ? b2f(bias[col]) : 0.f;
#pragma unroll
        for (int r = 0; r < RT; ++r) {
#pragma unroll
            for (int rr = 0; rr < 4; ++rr) {
                int m = m_base + r * 16 + quad * 4 + rr;
                if (m < M) {
                    float v = acc[r][t][rr] + bv;
                    if (relu) v = fmaxf(v, 0.f);
                    if (c32) ((float*)C)[(size_t)m * N + col] = v;
                    else ((__hip_bfloat16*)C)[(size_t)m * N + col] = __float2bfloat16(v);
                }
            }
        }
    }
}

// ---------------- el/er (feat: canonical bf16) ----------------
__global__ void k_el_er(const u16* __restrict__ feat, const u16* __restrict__ al,
                        const u16* __restrict__ ar, float* __restrict__ el,
                        float* __restrict__ er, int n_nodes) {
    int wave = threadIdx.x >> 6, lane = threadIdx.x & 63;
    int n = blockIdx.x * 4 + wave;
    if (n >= n_nodes) return;
#pragma unroll
    for (int h = 0; h < HEADS_H; ++h) {
        float fv = b2f(feat[(size_t)n * HDIM + h * 64 + lane]);
        float vl = fv * b2f(al[h * 64 + lane]);
        float vr = fv * b2f(ar[h * 64 + lane]);
        vl = wave_sum(vl);
        vr = wave_sum(vr);
        if (lane == 0) {
            el[n * HEADS_H + h] = vl;
            er[n * HEADS_H + h] = vr;
        }
    }
}

// ---------------- edge softmax per dst node ----------------
__global__ void k_softmax(const float* __restrict__ el, const float* __restrict__ er,
                          const int* __restrict__ src, const int* __restrict__ indptr,
                          const int* __restrict__ eids, float* __restrict__ alpha_perm,
                          int* __restrict__ src_perm, float* __restrict__ inv_s, int n_nodes) {
    int wave = threadIdx.x >> 6, lane = threadIdx.x & 63;
    int n = blockIdx.x * 4 + wave;
    if (n >= n_nodes) return;
    int beg = indptr[n], end = indptr[n + 1];

    float er_h[HEADS_H];
#pragma unroll
    for (int h = 0; h < HEADS_H; ++h) er_h[h] = er[n * HEADS_H + h];

    float mh[HEADS_H];
#pragma unroll
    for (int h = 0; h < HEADS_H; ++h) mh[h] = -INFINITY;
    for (int i = beg + lane; i < end; i += 64) {
        int s = src[eids[i]];
        src_perm[i] = s;
#pragma unroll
        for (int h = 0; h < HEADS_H; ++h) {
            float ev = el[s * HEADS_H + h] + er_h[h];
            ev = (ev > 0.f) ? ev : NEG_SLOPE * ev;
            mh[h] = fmaxf(mh[h], ev);
        }
    }
#pragma unroll
    for (int h = 0; h < HEADS_H; ++h) mh[h] = wave_max(mh[h]);

    float sh[HEADS_H] = {0.f, 0.f, 0.f};
    for (int i = beg + lane; i < end; i += 64) {
        int s = src_perm[i];
#pragma unroll
        for (int h = 0; h < HEADS_H; ++h) {
            float ev = el[s * HEADS_H + h] + er_h[h];
            ev = (ev > 0.f) ? ev : NEG_SLOPE * ev;
            float ex = __expf(ev - mh[h]);
            alpha_perm[(size_t)i * HEADS_H + h] = ex;
            sh[h] += ex;
        }
    }
#pragma unroll
    for (int h = 0; h < HEADS_H; ++h) {
        sh[h] = wave_sum(sh[h]);
        if (lane == 0) inv_s[n * HEADS_H + h] = (sh[h] > 0.f) ? 1.f / sh[h] : 0.f;
    }
}

// ---------------- aggregation: out = relu(inv_s * sum(ex*feat[src]) + b) ----------------
__global__ void k_agg(const u16* __restrict__ feat, const float* __restrict__ alpha_perm,
                      const int* __restrict__ src_perm, const int* __restrict__ indptr,
                      const float* __restrict__ inv_s, const u16* __restrict__ bias,
                      u16* __restrict__ outb, int n_nodes) {
    __shared__ int ssrc[CHUNK];
    __shared__ float salpha[CHUNK * HEADS_H];
    int n = blockIdx.x;
    int t = threadIdx.x;  // 0..191
    int h = t >> 6;
    int beg = indptr[n], end = indptr[n + 1];
    float acc = 0.f;

    for (int c0 = beg; c0 < end; c0 += CHUNK) {
        int len = min(CHUNK, end - c0);
        __syncthreads();
        for (int j = t; j < len; j += HDIM) ssrc[j] = src_perm[c0 + j];
        for (int j = t; j < HEADS_H * len; j += HDIM)
            salpha[j] = alpha_perm[(size_t)c0 * HEADS_H + j];
        __syncthreads();

        int j = 0;
        for (; j + 4 <= len; j += 4) {
            int s0 = ssrc[j], s1 = ssrc[j + 1], s2 = ssrc[j + 2], s3 = ssrc[j + 3];
            float f0 = b2f(feat[(size_t)s0 * HDIM + t]);
            float f1 = b2f(feat[(size_t)s1 * HDIM + t]);
            float f2 = b2f(feat[(size_t)s2 * HDIM + t]);
            float f3 = b2f(feat[(size_t)s3 * HDIM + t]);
            acc += salpha[j * HEADS_H + h] * f0;
            acc += salpha[(j + 1) * HEADS_H + h] * f1;
            acc += salpha[(j + 2) * HEADS_H + h] * f2;
            acc += salpha[(j + 3) * HEADS_H + h] * f3;
        }
        for (; j < len; ++j)
            acc += salpha[j * HEADS_H + h] * b2f(feat[(size_t)ssrc[j] * HDIM + t]);
    }

    float v = acc * inv_s[n * HEADS_H + h] + b2f(bias[t]);
    v = fmaxf(v, 0.f);
    outb[(size_t)n * HDIM + t] = f2b(v);
}

// ---------------- launch ----------------
extern "C" void kernel_launch(void* const* d_in, const int* in_sizes, int n_in,
                              void* d_out, int out_size, void* d_ws, size_t ws_size,
                              hipStream_t stream) {
    const void* features = d_in[0];
    const int* src = (const int*)d_in[1];
    const int* dst = (const int*)d_in[2];
    const void* W1 = d_in[3];
    const void* al1 = d_in[4];
    const void* ar1 = d_in[5];
    const void* b1 = d_in[6];
    const void* W2 = d_in[7];
    const void* al2 = d_in[8];
    const void* ar2 = d_in[9];
    const void* b2 = d_in[10];
    const void* Wm1 = d_in[11];
    const void* bm1 = d_in[12];
    const void* Wm2 = d_in[13];
    const void* bm2 = d_in[14];

    char* ws = (char*)d_ws;
    size_t off = 0;
    auto alloc = [&](size_t bytes) -> void* {
        void* p = ws + off;
        off = (off + bytes + 255) & ~(size_t)255;
        return p;
    };
    int* flag = (int*)alloc(4);
    u16* featb = (u16*)alloc((size_t)NN * HDIM * 2);
    u16* xbf = (u16*)alloc((size_t)NN * HDIM * 2);
    u16* mlph = (u16*)alloc((size_t)NN * 64 * 2);
    float* alpha_perm = (float*)alloc((size_t)NE * HEADS_H * 4);
    float* el = (float*)alloc((size_t)NN * HEADS_H * 4);
    float* er = (float*)alloc((size_t)NN * HEADS_H * 4);
    float* inv_s = (float*)alloc((size_t)NN * HEADS_H * 4);
    int* indptr = (int*)alloc((size_t)(NN + 1) * 4);
    int* cnt = (int*)alloc((size_t)NN * 4);
    int* eids = (int*)alloc((size_t)NE * 4);
    int* src_perm = (int*)alloc((size_t)NE * 4);
    int* partial = (int*)alloc((size_t)SCAN_NB * 4);
    int* offsets = (int*)alloc((size_t)SCAN_NB * 4);
    u16* W1T = (u16*)alloc((size_t)FIN * HDIM * 2);
    u16* W2T = (u16*)alloc((size_t)HDIM * HDIM * 2);
    u16* Wm1T = (u16*)alloc((size_t)HDIM * 64 * 2);
    u16* Wm2T = (u16*)alloc((size_t)64 * 64 * 2);
    u16* al1c = (u16*)alloc(HDIM * 2);
    u16* ar1c = (u16*)alloc(HDIM * 2);
    u16* b1c = (u16*)alloc(HDIM * 2);
    u16* al2c = (u16*)alloc(HDIM * 2);
    u16* ar2c = (u16*)alloc(HDIM * 2);
    u16* b2c = (u16*)alloc(HDIM * 2);
    u16* bm1c = (u16*)alloc(64 * 2);
    u16* bm2c = (u16*)alloc(64 * 2);

    if (ws_size < off) {
        k_fill_pattern<<<(out_size + 255) / 256, 256, 0, stream>>>((u16*)d_out, out_size, 0x3F80);
        return;
    }

    k_sniff<<<1, 256, 0, stream>>>((const unsigned*)features, flag);

    k_cvt8<<<8, 256, 0, stream>>>(al1, ar1, b1, al2, ar2, b2, bm1, bm2, al1c, ar1c, b1c, al2c,
                                  ar2c, b2c, bm1c, bm2c, flag);
    {
        const int tot = FIN * HDIM + HDIM * HDIM + HDIM * 64 + 64 * 64;
        k_transpose4<<<(tot + 255) / 256, 256, 0, stream>>>(W1, W2, Wm1, Wm2, W1T, W2T, Wm1T,
                                                            Wm2T, flag);
    }

    // CSR by dst (hierarchical scan replaces the 110 µs single-block scan)
    k_zero<<<(NN + 255) / 256, 256, 0, stream>>>(cnt, NN);
    k_count<<<(NE + 255) / 256, 256, 0, stream>>>(dst, cnt, NE);
    k_scan_partial<<<SCAN_NB, 256, 0, stream>>>(cnt, partial);
    k_scan_mid<<<1, 128, 0, stream>>>(partial, offsets, indptr);
    k_scan_final<<<SCAN_NB, 256, 0, stream>>>(cnt, offsets, indptr);
    k_fill<<<(NE + 255) / 256, 256, 0, stream>>>(dst, cnt, eids, NE);

    const int g32 = (NN + 31) / 32;  // RT=2 grid

    // GAT layer 1
    k_gemm<12, 2><<<g32, 64, 0, stream>>>(features, 1, W1T, featb, 0, nullptr, flag, NN, FIN, 0);
    k_el_er<<<(NN + 3) / 4, 256, 0, stream>>>(featb, al1c, ar1c, el, er, NN);
    k_softmax<<<(NN + 3) / 4, 256, 0, stream>>>(el, er, src, indptr, eids, alpha_perm, src_perm,
                                                inv_s, NN);
    k_agg<<<NN, HDIM, 0, stream>>>(featb, alpha_perm, src_perm, indptr, inv_s, b1c, xbf, NN);

    // GAT layer 2
    k_gemm<12, 2><<<g32, 64, 0, stream>>>(xbf, 0, W2T, featb, 0, nullptr, flag, NN, HDIM, 0);
    k_el_er<<<(NN + 3) / 4, 256, 0, stream>>>(featb, al2c, ar2c, el, er, NN);
    k_softmax<<<(NN + 3) / 4, 256, 0, stream>>>(el, er, src, indptr, eids, alpha_perm, src_perm,
                                                inv_s, NN);
    k_agg<<<NN, HDIM, 0, stream>>>(featb, alpha_perm, src_perm, indptr, inv_s, b2c, xbf, NN);

    // MLP
    k_gemm<4, 2><<<g32, 64, 0, stream>>>(xbf, 0, Wm1T, mlph, 0, bm1c, flag, NN, HDIM, 1);
    k_gemm<4, 2><<<g32, 64, 0, stream>>>(mlph, 0, Wm2T, d_out, 1, bm2c, flag, NN, 64, 0);
}

// Round 6
// 497.935 us; speedup vs baseline: 1.8915x; 1.1113x over previous
//
#include <hip/hip_runtime.h>
#include <hip/hip_bf16.h>

// ---- problem constants (fixed by reference) ----
#define NN 50000
#define NE 800000
#define FIN 256
#define HEADS_H 3
#define HDIM 192
#define NEG_SLOPE 0.2f
#define CHUNK 128        // edges staged in LDS per iteration in k_agg
#define SCAN_ELEMS 512   // elements per scan block
#define SCAN_NB ((NN + SCAN_ELEMS - 1) / SCAN_ELEMS)  // 98

typedef __attribute__((ext_vector_type(8))) short frag8;
typedef __attribute__((ext_vector_type(4))) float f32x4;
typedef unsigned short u16;

__device__ inline u16 f2b(float x) {
    __hip_bfloat16 h = __float2bfloat16(x);
    return __builtin_bit_cast(u16, h);
}
__device__ inline float b2f(u16 b) {
    __hip_bfloat16 h = __builtin_bit_cast(__hip_bfloat16, b);
    return __bfloat162float(h);
}
// bf16 pair unpack from u32 (1 VALU op each)
__device__ inline float b2f_lo(unsigned v) { return __builtin_bit_cast(float, v << 16); }
__device__ inline float b2f_hi(unsigned v) { return __builtin_bit_cast(float, v & 0xffff0000u); }

__device__ inline float wave_sum(float v) {
#pragma unroll
    for (int off = 32; off > 0; off >>= 1) v += __shfl_xor(v, off, 64);
    return v;
}
__device__ inline int wave_sum_i(int v) {
#pragma unroll
    for (int off = 32; off > 0; off >>= 1) v += __shfl_xor(v, off, 64);
    return v;
}
__device__ inline float wave_max(float v) {
#pragma unroll
    for (int off = 32; off > 0; off >>= 1) v = fmaxf(v, __shfl_xor(v, off, 64));
    return v;
}

// ---------------- utility ----------------
__global__ void k_fill_pattern(u16* __restrict__ p, int n, u16 v) {
    int i = blockIdx.x * blockDim.x + threadIdx.x;
    if (i < n) p[i] = v;
}
__global__ void k_zero(int* __restrict__ p, int n) {
    int i = blockIdx.x * blockDim.x + threadIdx.x;
    if (i < n) p[i] = 0;
}

// dtype sniffer
__global__ void k_sniff(const unsigned* __restrict__ p, int* __restrict__ flag) {
    __shared__ int cnt_s;
    if (threadIdx.x == 0) cnt_s = 0;
    __syncthreads();
    int c = 0;
    for (int i = threadIdx.x; i < 4096; i += 256) {
        float v = __builtin_bit_cast(float, p[i]);
        float a = fabsf(v);
        if (a > 1e-4f && a < 100.f) c++;
    }
    atomicAdd(&cnt_s, c);
    __syncthreads();
    if (threadIdx.x == 0) *flag = (cnt_s > 2048) ? 1 : 0;  // 1 = inputs are fp32
}

__global__ void k_cvt8(const void* i0, const void* i1, const void* i2, const void* i3,
                       const void* i4, const void* i5, const void* i6, const void* i7,
                       u16* o0, u16* o1, u16* o2, u16* o3, u16* o4, u16* o5, u16* o6, u16* o7,
                       const int* __restrict__ flag) {
    const void* ins[8] = {i0, i1, i2, i3, i4, i5, i6, i7};
    u16* outs[8] = {o0, o1, o2, o3, o4, o5, o6, o7};
    const int ns[8] = {HDIM, HDIM, HDIM, HDIM, HDIM, HDIM, 64, 64};
    int b = blockIdx.x;
    int n = ns[b];
    const void* in = ins[b];
    u16* out = outs[b];
    int f = *flag;
    for (int i = threadIdx.x; i < n; i += 256) {
        out[i] = f ? f2b(((const float*)in)[i]) : ((const u16*)in)[i];
    }
}

// all 4 weight transposes in ONE dispatch: T[n*K+k] = cvt(B[k*N+n])
__global__ void k_transpose4(const void* __restrict__ B0, const void* __restrict__ B1,
                             const void* __restrict__ B2, const void* __restrict__ B3,
                             u16* __restrict__ T0, u16* __restrict__ T1, u16* __restrict__ T2,
                             u16* __restrict__ T3, const int* __restrict__ flag) {
    const int n0 = FIN * HDIM, n1 = HDIM * HDIM, n2 = HDIM * 64, n3 = 64 * 64;
    int gi = blockIdx.x * 256 + threadIdx.x;
    const void* B;
    u16* T;
    int K, N, i;
    if (gi < n0) { B = B0; T = T0; K = FIN; N = HDIM; i = gi; }
    else if (gi < n0 + n1) { B = B1; T = T1; K = HDIM; N = HDIM; i = gi - n0; }
    else if (gi < n0 + n1 + n2) { B = B2; T = T2; K = HDIM; N = 64; i = gi - n0 - n1; }
    else if (gi < n0 + n1 + n2 + n3) { B = B3; T = T3; K = 64; N = 64; i = gi - n0 - n1 - n2; }
    else return;
    int k = i / N, n = i - k * N;
    u16 v = (*flag) ? f2b(((const float*)B)[i]) : ((const u16*)B)[i];
    T[n * K + k] = v;
}

// ---------------- CSR build ----------------
__global__ void k_count(const int* __restrict__ dst, int* __restrict__ cnt, int E) {
    int e = blockIdx.x * blockDim.x + threadIdx.x;
    if (e < E) atomicAdd(&cnt[dst[e]], 1);
}

__global__ void k_scan_partial(const int* __restrict__ cnt, int* __restrict__ partial) {
    int b = blockIdx.x, t = threadIdx.x;
    int i0 = b * SCAN_ELEMS + t * 2;
    int v = 0;
    if (i0 < NN) v += cnt[i0];
    if (i0 + 1 < NN) v += cnt[i0 + 1];
    v = wave_sum_i(v);
    __shared__ int wsum[4];
    if ((t & 63) == 0) wsum[t >> 6] = v;
    __syncthreads();
    if (t == 0) partial[b] = wsum[0] + wsum[1] + wsum[2] + wsum[3];
}

__global__ void k_scan_mid(const int* __restrict__ partial, int* __restrict__ offsets,
                           int* __restrict__ indptr) {
    __shared__ int s[SCAN_NB];
    int t = threadIdx.x;  // 128 >= SCAN_NB
    if (t < SCAN_NB) s[t] = partial[t];
    __syncthreads();
    for (int off = 1; off < SCAN_NB; off <<= 1) {
        int v = (t >= off && t < SCAN_NB) ? s[t - off] : 0;
        __syncthreads();
        if (t < SCAN_NB) s[t] += v;
        __syncthreads();
    }
    if (t < SCAN_NB) offsets[t] = (t == 0) ? 0 : s[t - 1];
    if (t == 0) indptr[NN] = s[SCAN_NB - 1];
}

__global__ void k_scan_final(int* __restrict__ cnt, const int* __restrict__ offsets,
                             int* __restrict__ indptr) {
    __shared__ int tsum[256];
    int b = blockIdx.x, t = threadIdx.x;
    int i0 = b * SCAN_ELEMS + t * 2;
    int c0 = (i0 < NN) ? cnt[i0] : 0;
    int c1 = (i0 + 1 < NN) ? cnt[i0 + 1] : 0;
    tsum[t] = c0 + c1;
    __syncthreads();
    for (int off = 1; off < 256; off <<= 1) {
        int v = (t >= off) ? tsum[t - off] : 0;
        __syncthreads();
        tsum[t] += v;
        __syncthreads();
    }
    int excl = offsets[b] + ((t == 0) ? 0 : tsum[t - 1]);
    if (i0 < NN) { indptr[i0] = excl; cnt[i0] = excl; }
    if (i0 + 1 < NN) { indptr[i0 + 1] = excl + c0; cnt[i0 + 1] = excl + c0; }
}

__global__ void k_fill(const int* __restrict__ dst, int* __restrict__ cursor,
                       int* __restrict__ eids, int E) {
    int e = blockIdx.x * blockDim.x + threadIdx.x;
    if (e < E) {
        int p = atomicAdd(&cursor[dst[e]], 1);
        eids[p] = e;
    }
}

// ---------------- MFMA GEMM + fused el/er epilogue ----------------
// C[M,N] = A[M,K]*B[K,N]. If elp != nullptr (NT==12 only): el[m][h] = sum_col C*al, er likewise.
template <int NT, int RT>
__global__ __launch_bounds__(64) void k_gemm(const void* __restrict__ A, int a_dual,
                                             const u16* __restrict__ BT, void* __restrict__ C,
                                             int c_dual, const u16* __restrict__ bias,
                                             const int* __restrict__ flag, int M, int K,
                                             int relu, float* __restrict__ elp,
                                             float* __restrict__ erp,
                                             const u16* __restrict__ al,
                                             const u16* __restrict__ ar) {
    const int lane = threadIdx.x;
    const int c16 = lane & 15;
    const int quad = lane >> 4;
    const int m_base = blockIdx.x * (16 * RT);
    const int f = *flag;
    const bool a32 = a_dual && f;
    const bool c32 = c_dual && f;

    int arow[RT];
#pragma unroll
    for (int r = 0; r < RT; ++r) {
        int m = m_base + r * 16 + c16;
        arow[r] = (m < M) ? m : (M - 1);
    }

    f32x4 acc[RT][NT];
#pragma unroll
    for (int r = 0; r < RT; ++r)
#pragma unroll
        for (int t = 0; t < NT; ++t) acc[r][t] = (f32x4)0.f;

    for (int k0 = 0; k0 < K; k0 += 32) {
        frag8 a[RT];
#pragma unroll
        for (int r = 0; r < RT; ++r) {
            if (a32) {
                const float* ap = (const float*)A + (size_t)arow[r] * K + k0 + quad * 8;
                f32x4 f0 = *(const f32x4*)ap;
                f32x4 f1 = *(const f32x4*)(ap + 4);
                a[r][0] = (short)f2b(f0[0]); a[r][1] = (short)f2b(f0[1]);
                a[r][2] = (short)f2b(f0[2]); a[r][3] = (short)f2b(f0[3]);
                a[r][4] = (short)f2b(f1[0]); a[r][5] = (short)f2b(f1[1]);
                a[r][6] = (short)f2b(f1[2]); a[r][7] = (short)f2b(f1[3]);
            } else {
                a[r] = *(const frag8*)((const u16*)A + (size_t)arow[r] * K + k0 + quad * 8);
            }
        }
#pragma unroll
        for (int t = 0; t < NT; ++t) {
            frag8 b = *(const frag8*)(BT + (size_t)(t * 16 + c16) * K + k0 + quad * 8);
#pragma unroll
            for (int r = 0; r < RT; ++r)
                acc[r][t] = __builtin_amdgcn_mfma_f32_16x16x32_bf16(a[r], b, acc[r][t], 0, 0, 0);
        }
    }

    const int N = NT * 16;
#pragma unroll
    for (int t = 0; t < NT; ++t) {
        int col = t * 16 + c16;
        float bv = bias ? b2f(bias[col]) : 0.f;
#pragma unroll
        for (int r = 0; r < RT; ++r) {
#pragma unroll
            for (int rr = 0; rr < 4; ++rr) {
                int m = m_base + r * 16 + quad * 4 + rr;
                if (m < M) {
                    float v = acc[r][t][rr] + bv;
                    if (relu) v = fmaxf(v, 0.f);
                    if (c32) ((float*)C)[(size_t)m * N + col] = v;
                    else ((__hip_bfloat16*)C)[(size_t)m * N + col] = __float2bfloat16(v);
                }
            }
        }
    }

    // fused el/er epilogue (GAT layers only; NT==12 => 3 heads x 4 col-tiles)
    if (NT == 12 && elp) {
        float alv[NT], arv[NT];
#pragma unroll
        for (int t = 0; t < NT; ++t) {
            alv[t] = b2f(al[t * 16 + c16]);
            arv[t] = b2f(ar[t * 16 + c16]);
        }
#pragma unroll
        for (int r = 0; r < RT; ++r) {
#pragma unroll
            for (int rr = 0; rr < 4; ++rr) {
                int m = m_base + r * 16 + quad * 4 + rr;
                float pl[HEADS_H] = {0.f, 0.f, 0.f};
                float pr[HEADS_H] = {0.f, 0.f, 0.f};
#pragma unroll
                for (int t = 0; t < NT; ++t) {
                    int h = t >> 2;
                    pl[h] += acc[r][t][rr] * alv[t];
                    pr[h] += acc[r][t][rr] * arv[t];
                }
#pragma unroll
                for (int h = 0; h < HEADS_H; ++h) {
#pragma unroll
                    for (int off = 1; off < 16; off <<= 1) {
                        pl[h] += __shfl_xor(pl[h], off, 64);
                        pr[h] += __shfl_xor(pr[h], off, 64);
                    }
                    if (c16 == 0 && m < M) {
                        elp[m * HEADS_H + h] = pl[h];
                        erp[m * HEADS_H + h] = pr[h];
                    }
                }
            }
        }
    }
}

// ---------------- edge softmax per dst node ----------------
__global__ void k_softmax(const float* __restrict__ el, const float* __restrict__ er,
                          const int* __restrict__ src, const int* __restrict__ indptr,
                          const int* __restrict__ eids, float* __restrict__ alpha_perm,
                          int* __restrict__ src_perm, float* __restrict__ inv_s, int n_nodes) {
    int wave = threadIdx.x >> 6, lane = threadIdx.x & 63;
    int n = blockIdx.x * 4 + wave;
    if (n >= n_nodes) return;
    int beg = indptr[n], end = indptr[n + 1];

    float er_h[HEADS_H];
#pragma unroll
    for (int h = 0; h < HEADS_H; ++h) er_h[h] = er[n * HEADS_H + h];

    float mh[HEADS_H];
#pragma unroll
    for (int h = 0; h < HEADS_H; ++h) mh[h] = -INFINITY;
    for (int i = beg + lane; i < end; i += 64) {
        int s = src[eids[i]];
        src_perm[i] = s;
#pragma unroll
        for (int h = 0; h < HEADS_H; ++h) {
            float ev = el[s * HEADS_H + h] + er_h[h];
            ev = (ev > 0.f) ? ev : NEG_SLOPE * ev;
            mh[h] = fmaxf(mh[h], ev);
        }
    }
#pragma unroll
    for (int h = 0; h < HEADS_H; ++h) mh[h] = wave_max(mh[h]);

    float sh[HEADS_H] = {0.f, 0.f, 0.f};
    for (int i = beg + lane; i < end; i += 64) {
        int s = src_perm[i];
#pragma unroll
        for (int h = 0; h < HEADS_H; ++h) {
            float ev = el[s * HEADS_H + h] + er_h[h];
            ev = (ev > 0.f) ? ev : NEG_SLOPE * ev;
            float ex = __expf(ev - mh[h]);
            alpha_perm[(size_t)i * HEADS_H + h] = ex;
            sh[h] += ex;
        }
    }
#pragma unroll
    for (int h = 0; h < HEADS_H; ++h) {
        sh[h] = wave_sum(sh[h]);
        if (lane == 0) inv_s[n * HEADS_H + h] = (sh[h] > 0.f) ? 1.f / sh[h] : 0.f;
    }
}

// ---------------- aggregation: out = relu(inv_s * sum(ex*feat[src]) + b) ----------------
// 192 threads = 2 edge-slots x 96 threads; each thread owns 2 dims (u32 loads).
// 8 independent feat loads in flight (2 slots x 4-unroll).
__global__ void k_agg(const u16* __restrict__ feat, const float* __restrict__ alpha_perm,
                      const int* __restrict__ src_perm, const int* __restrict__ indptr,
                      const float* __restrict__ inv_s, const u16* __restrict__ bias,
                      u16* __restrict__ outb, int n_nodes) {
    __shared__ int ssrc[CHUNK];
    __shared__ float salpha[CHUNK * HEADS_H];
    __shared__ float spart[96 * 2];
    int n = blockIdx.x;
    int t = threadIdx.x;       // 0..191
    int slot = t / 96;         // 0 or 1
    int u = t - slot * 96;     // 0..95 -> dims 2u, 2u+1
    int h = u >> 5;            // head
    int beg = indptr[n], end = indptr[n + 1];
    float ax = 0.f, ay = 0.f;
    const u16* fbase = feat + 2 * u;

    for (int c0 = beg; c0 < end; c0 += CHUNK) {
        int len = min(CHUNK, end - c0);
        __syncthreads();
        for (int j = t; j < len; j += HDIM) ssrc[j] = src_perm[c0 + j];
        for (int j = t; j < HEADS_H * len; j += HDIM)
            salpha[j] = alpha_perm[(size_t)c0 * HEADS_H + j];
        __syncthreads();

        int j = slot;
        for (; j + 6 < len; j += 8) {
            int s0 = ssrc[j], s1 = ssrc[j + 2], s2 = ssrc[j + 4], s3 = ssrc[j + 6];
            unsigned v0 = *(const unsigned*)(fbase + (size_t)s0 * HDIM);
            unsigned v1 = *(const unsigned*)(fbase + (size_t)s1 * HDIM);
            unsigned v2 = *(const unsigned*)(fbase + (size_t)s2 * HDIM);
            unsigned v3 = *(const unsigned*)(fbase + (size_t)s3 * HDIM);
            float a0 = salpha[j * HEADS_H + h];
            float a1 = salpha[(j + 2) * HEADS_H + h];
            float a2 = salpha[(j + 4) * HEADS_H + h];
            float a3 = salpha[(j + 6) * HEADS_H + h];
            ax += a0 * b2f_lo(v0); ay += a0 * b2f_hi(v0);
            ax += a1 * b2f_lo(v1); ay += a1 * b2f_hi(v1);
            ax += a2 * b2f_lo(v2); ay += a2 * b2f_hi(v2);
            ax += a3 * b2f_lo(v3); ay += a3 * b2f_hi(v3);
        }
        for (; j < len; j += 2) {
            int s = ssrc[j];
            unsigned v = *(const unsigned*)(fbase + (size_t)s * HDIM);
            float a = salpha[j * HEADS_H + h];
            ax += a * b2f_lo(v); ay += a * b2f_hi(v);
        }
    }

    __syncthreads();
    if (slot == 1) { spart[u * 2] = ax; spart[u * 2 + 1] = ay; }
    __syncthreads();
    if (slot == 0) {
        float is = inv_s[n * HEADS_H + h];
        unsigned bv = *(const unsigned*)(bias + 2 * u);
        float vx = (ax + spart[u * 2]) * is + b2f_lo(bv);
        float vy = (ay + spart[u * 2 + 1]) * is + b2f_hi(bv);
        vx = fmaxf(vx, 0.f);
        vy = fmaxf(vy, 0.f);
        unsigned o = (unsigned)f2b(vx) | ((unsigned)f2b(vy) << 16);
        *(unsigned*)(outb + (size_t)n * HDIM + 2 * u) = o;
    }
}

// ---------------- launch ----------------
extern "C" void kernel_launch(void* const* d_in, const int* in_sizes, int n_in,
                              void* d_out, int out_size, void* d_ws, size_t ws_size,
                              hipStream_t stream) {
    const void* features = d_in[0];
    const int* src = (const int*)d_in[1];
    const int* dst = (const int*)d_in[2];
    const void* W1 = d_in[3];
    const void* al1 = d_in[4];
    const void* ar1 = d_in[5];
    const void* b1 = d_in[6];
    const void* W2 = d_in[7];
    const void* al2 = d_in[8];
    const void* ar2 = d_in[9];
    const void* b2 = d_in[10];
    const void* Wm1 = d_in[11];
    const void* bm1 = d_in[12];
    const void* Wm2 = d_in[13];
    const void* bm2 = d_in[14];

    char* ws = (char*)d_ws;
    size_t off = 0;
    auto alloc = [&](size_t bytes) -> void* {
        void* p = ws + off;
        off = (off + bytes + 255) & ~(size_t)255;
        return p;
    };
    int* flag = (int*)alloc(4);
    u16* featb = (u16*)alloc((size_t)NN * HDIM * 2);
    u16* xbf = (u16*)alloc((size_t)NN * HDIM * 2);
    u16* mlph = (u16*)alloc((size_t)NN * 64 * 2);
    float* alpha_perm = (float*)alloc((size_t)NE * HEADS_H * 4);
    float* el = (float*)alloc((size_t)NN * HEADS_H * 4);
    float* er = (float*)alloc((size_t)NN * HEADS_H * 4);
    float* inv_s = (float*)alloc((size_t)NN * HEADS_H * 4);
    int* indptr = (int*)alloc((size_t)(NN + 1) * 4);
    int* cnt = (int*)alloc((size_t)NN * 4);
    int* eids = (int*)alloc((size_t)NE * 4);
    int* src_perm = (int*)alloc((size_t)NE * 4);
    int* partial = (int*)alloc((size_t)SCAN_NB * 4);
    int* offsets = (int*)alloc((size_t)SCAN_NB * 4);
    u16* W1T = (u16*)alloc((size_t)FIN * HDIM * 2);
    u16* W2T = (u16*)alloc((size_t)HDIM * HDIM * 2);
    u16* Wm1T = (u16*)alloc((size_t)HDIM * 64 * 2);
    u16* Wm2T = (u16*)alloc((size_t)64 * 64 * 2);
    u16* al1c = (u16*)alloc(HDIM * 2);
    u16* ar1c = (u16*)alloc(HDIM * 2);
    u16* b1c = (u16*)alloc(HDIM * 2);
    u16* al2c = (u16*)alloc(HDIM * 2);
    u16* ar2c = (u16*)alloc(HDIM * 2);
    u16* b2c = (u16*)alloc(HDIM * 2);
    u16* bm1c = (u16*)alloc(64 * 2);
    u16* bm2c = (u16*)alloc(64 * 2);

    if (ws_size < off) {
        k_fill_pattern<<<(out_size + 255) / 256, 256, 0, stream>>>((u16*)d_out, out_size, 0x3F80);
        return;
    }

    k_sniff<<<1, 256, 0, stream>>>((const unsigned*)features, flag);

    k_cvt8<<<8, 256, 0, stream>>>(al1, ar1, b1, al2, ar2, b2, bm1, bm2, al1c, ar1c, b1c, al2c,
                                  ar2c, b2c, bm1c, bm2c, flag);
    {
        const int tot = FIN * HDIM + HDIM * HDIM + HDIM * 64 + 64 * 64;
        k_transpose4<<<(tot + 255) / 256, 256, 0, stream>>>(W1, W2, Wm1, Wm2, W1T, W2T, Wm1T,
                                                            Wm2T, flag);
    }

    // CSR by dst
    k_zero<<<(NN + 255) / 256, 256, 0, stream>>>(cnt, NN);
    k_count<<<(NE + 255) / 256, 256, 0, stream>>>(dst, cnt, NE);
    k_scan_partial<<<SCAN_NB, 256, 0, stream>>>(cnt, partial);
    k_scan_mid<<<1, 128, 0, stream>>>(partial, offsets, indptr);
    k_scan_final<<<SCAN_NB, 256, 0, stream>>>(cnt, offsets, indptr);
    k_fill<<<(NE + 255) / 256, 256, 0, stream>>>(dst, cnt, eids, NE);

    const int g32 = (NN + 31) / 32;  // RT=2 grid

    // GAT layer 1 (el/er fused into GEMM epilogue)
    k_gemm<12, 2><<<g32, 64, 0, stream>>>(features, 1, W1T, featb, 0, nullptr, flag, NN, FIN, 0,
                                          el, er, al1c, ar1c);
    k_softmax<<<(NN + 3) / 4, 256, 0, stream>>>(el, er, src, indptr, eids, alpha_perm, src_perm,
                                                inv_s, NN);
    k_agg<<<NN, HDIM, 0, stream>>>(featb, alpha_perm, src_perm, indptr, inv_s, b1c, xbf, NN);

    // GAT layer 2
    k_gemm<12, 2><<<g32, 64, 0, stream>>>(xbf, 0, W2T, featb, 0, nullptr, flag, NN, HDIM, 0,
                                          el, er, al2c, ar2c);
    k_softmax<<<(NN + 3) / 4, 256, 0, stream>>>(el, er, src, indptr, eids, alpha_perm, src_perm,
                                                inv_s, NN);
    k_agg<<<NN, HDIM, 0, stream>>>(featb, alpha_perm, src_perm, indptr, inv_s, b2c, xbf, NN);

    // MLP
    k_gemm<4, 2><<<g32, 64, 0, stream>>>(xbf, 0, Wm1T, mlph, 0, bm1c, flag, NN, HDIM, 1, nullptr,
                                         nullptr, nullptr, nullptr);
    k_gemm<4, 2><<<g32, 64, 0, stream>>>(mlph, 0, Wm2T, d_out, 1, bm2c, flag, NN, 64, 0, nullptr,
                                         nullptr, nullptr, nullptr);
}

// Round 7
// 461.251 us; speedup vs baseline: 2.0420x; 1.0795x over previous
//
#include <hip/hip_runtime.h>
#include <hip/hip_bf16.h>

// ---- problem constants (fixed by reference) ----
#define NN 50000
#define NE 800000
#define FIN 256
#define HEADS_H 3
#define HDIM 192
#define NEG_SLOPE 0.2f
#define CHUNK 128        // edges staged in LDS per iteration in k_agg
#define SCAN_ELEMS 512   // elements per scan block
#define SCAN_NB ((NN + SCAN_ELEMS - 1) / SCAN_ELEMS)  // 98

typedef __attribute__((ext_vector_type(8))) short frag8;
typedef __attribute__((ext_vector_type(4))) float f32x4;
typedef __attribute__((ext_vector_type(2))) unsigned u32x2;
typedef unsigned short u16;

__device__ inline u16 f2b(float x) {
    __hip_bfloat16 h = __float2bfloat16(x);
    return __builtin_bit_cast(u16, h);
}
__device__ inline float b2f(u16 b) {
    __hip_bfloat16 h = __builtin_bit_cast(__hip_bfloat16, b);
    return __bfloat162float(h);
}
// bf16 pair unpack from u32 (1 VALU op each)
__device__ inline float b2f_lo(unsigned v) { return __builtin_bit_cast(float, v << 16); }
__device__ inline float b2f_hi(unsigned v) { return __builtin_bit_cast(float, v & 0xffff0000u); }

__device__ inline float wave_sum(float v) {
#pragma unroll
    for (int off = 32; off > 0; off >>= 1) v += __shfl_xor(v, off, 64);
    return v;
}
__device__ inline int wave_sum_i(int v) {
#pragma unroll
    for (int off = 32; off > 0; off >>= 1) v += __shfl_xor(v, off, 64);
    return v;
}

// ---------------- utility ----------------
__global__ void k_fill_pattern(u16* __restrict__ p, int n, u16 v) {
    int i = blockIdx.x * blockDim.x + threadIdx.x;
    if (i < n) p[i] = v;
}
__global__ void k_zero(int* __restrict__ p, int n) {
    int i = blockIdx.x * blockDim.x + threadIdx.x;
    if (i < n) p[i] = 0;
}

// dtype sniffer
__global__ void k_sniff(const unsigned* __restrict__ p, int* __restrict__ flag) {
    __shared__ int cnt_s;
    if (threadIdx.x == 0) cnt_s = 0;
    __syncthreads();
    int c = 0;
    for (int i = threadIdx.x; i < 4096; i += 256) {
        float v = __builtin_bit_cast(float, p[i]);
        float a = fabsf(v);
        if (a > 1e-4f && a < 100.f) c++;
    }
    atomicAdd(&cnt_s, c);
    __syncthreads();
    if (threadIdx.x == 0) *flag = (cnt_s > 2048) ? 1 : 0;  // 1 = inputs are fp32
}

__global__ void k_cvt8(const void* i0, const void* i1, const void* i2, const void* i3,
                       const void* i4, const void* i5, const void* i6, const void* i7,
                       u16* o0, u16* o1, u16* o2, u16* o3, u16* o4, u16* o5, u16* o6, u16* o7,
                       const int* __restrict__ flag) {
    const void* ins[8] = {i0, i1, i2, i3, i4, i5, i6, i7};
    u16* outs[8] = {o0, o1, o2, o3, o4, o5, o6, o7};
    const int ns[8] = {HDIM, HDIM, HDIM, HDIM, HDIM, HDIM, 64, 64};
    int b = blockIdx.x;
    int n = ns[b];
    const void* in = ins[b];
    u16* out = outs[b];
    int f = *flag;
    for (int i = threadIdx.x; i < n; i += 256) {
        out[i] = f ? f2b(((const float*)in)[i]) : ((const u16*)in)[i];
    }
}

// all 4 weight transposes in ONE dispatch: T[n*K+k] = cvt(B[k*N+n])
__global__ void k_transpose4(const void* __restrict__ B0, const void* __restrict__ B1,
                             const void* __restrict__ B2, const void* __restrict__ B3,
                             u16* __restrict__ T0, u16* __restrict__ T1, u16* __restrict__ T2,
                             u16* __restrict__ T3, const int* __restrict__ flag) {
    const int n0 = FIN * HDIM, n1 = HDIM * HDIM, n2 = HDIM * 64, n3 = 64 * 64;
    int gi = blockIdx.x * 256 + threadIdx.x;
    const void* B;
    u16* T;
    int K, N, i;
    if (gi < n0) { B = B0; T = T0; K = FIN; N = HDIM; i = gi; }
    else if (gi < n0 + n1) { B = B1; T = T1; K = HDIM; N = HDIM; i = gi - n0; }
    else if (gi < n0 + n1 + n2) { B = B2; T = T2; K = HDIM; N = 64; i = gi - n0 - n1; }
    else if (gi < n0 + n1 + n2 + n3) { B = B3; T = T3; K = 64; N = 64; i = gi - n0 - n1 - n2; }
    else return;
    int k = i / N, n = i - k * N;
    u16 v = (*flag) ? f2b(((const float*)B)[i]) : ((const u16*)B)[i];
    T[n * K + k] = v;
}

// ---------------- CSR build ----------------
__global__ void k_count(const int* __restrict__ dst, int* __restrict__ cnt, int E) {
    int e = blockIdx.x * blockDim.x + threadIdx.x;
    if (e < E) atomicAdd(&cnt[dst[e]], 1);
}

__global__ void k_scan_partial(const int* __restrict__ cnt, int* __restrict__ partial) {
    int b = blockIdx.x, t = threadIdx.x;
    int i0 = b * SCAN_ELEMS + t * 2;
    int v = 0;
    if (i0 < NN) v += cnt[i0];
    if (i0 + 1 < NN) v += cnt[i0 + 1];
    v = wave_sum_i(v);
    __shared__ int wsum[4];
    if ((t & 63) == 0) wsum[t >> 6] = v;
    __syncthreads();
    if (t == 0) partial[b] = wsum[0] + wsum[1] + wsum[2] + wsum[3];
}

__global__ void k_scan_mid(const int* __restrict__ partial, int* __restrict__ offsets,
                           int* __restrict__ indptr) {
    __shared__ int s[SCAN_NB];
    int t = threadIdx.x;  // 128 >= SCAN_NB
    if (t < SCAN_NB) s[t] = partial[t];
    __syncthreads();
    for (int off = 1; off < SCAN_NB; off <<= 1) {
        int v = (t >= off && t < SCAN_NB) ? s[t - off] : 0;
        __syncthreads();
        if (t < SCAN_NB) s[t] += v;
        __syncthreads();
    }
    if (t < SCAN_NB) offsets[t] = (t == 0) ? 0 : s[t - 1];
    if (t == 0) indptr[NN] = s[SCAN_NB - 1];
}

__global__ void k_scan_final(int* __restrict__ cnt, const int* __restrict__ offsets,
                             int* __restrict__ indptr) {
    __shared__ int tsum[256];
    int b = blockIdx.x, t = threadIdx.x;
    int i0 = b * SCAN_ELEMS + t * 2;
    int c0 = (i0 < NN) ? cnt[i0] : 0;
    int c1 = (i0 + 1 < NN) ? cnt[i0 + 1] : 0;
    tsum[t] = c0 + c1;
    __syncthreads();
    for (int off = 1; off < 256; off <<= 1) {
        int v = (t >= off) ? tsum[t - off] : 0;
        __syncthreads();
        tsum[t] += v;
        __syncthreads();
    }
    int excl = offsets[b] + ((t == 0) ? 0 : tsum[t - 1]);
    if (i0 < NN) { indptr[i0] = excl; cnt[i0] = excl; }
    if (i0 + 1 < NN) { indptr[i0 + 1] = excl + c0; cnt[i0 + 1] = excl + c0; }
}

// writes CSR-ordered src directly (no eids indirection)
__global__ void k_fill(const int* __restrict__ dst, const int* __restrict__ srcv,
                       int* __restrict__ cursor, int* __restrict__ src_perm, int E) {
    int e = blockIdx.x * blockDim.x + threadIdx.x;
    if (e < E) {
        int p = atomicAdd(&cursor[dst[e]], 1);
        src_perm[p] = srcv[e];
    }
}

// ---------------- MFMA GEMM + fused el/er epilogue, 2-stage register prefetch ----
// K/32 must be EVEN (K in {256,192,64} here).
template <int NT, int RT>
__global__ __launch_bounds__(64) void k_gemm(const void* __restrict__ A, int a_dual,
                                             const u16* __restrict__ BT, void* __restrict__ C,
                                             int c_dual, const u16* __restrict__ bias,
                                             const int* __restrict__ flag, int M, int K,
                                             int relu, float* __restrict__ elp,
                                             float* __restrict__ erp,
                                             const u16* __restrict__ al,
                                             const u16* __restrict__ ar) {
    const int lane = threadIdx.x;
    const int c16 = lane & 15;
    const int quad = lane >> 4;
    const int m_base = blockIdx.x * (16 * RT);
    const int f = *flag;
    const bool a32 = a_dual && f;
    const bool c32 = c_dual && f;

    int arow[RT];
#pragma unroll
    for (int r = 0; r < RT; ++r) {
        int m = m_base + r * 16 + c16;
        arow[r] = (m < M) ? m : (M - 1);
    }

    f32x4 acc[RT][NT];
#pragma unroll
    for (int r = 0; r < RT; ++r)
#pragma unroll
        for (int t = 0; t < NT; ++t) acc[r][t] = (f32x4)0.f;

    auto loadA = [&](int k0, frag8* a) {
#pragma unroll
        for (int r = 0; r < RT; ++r) {
            if (a32) {
                const float* ap = (const float*)A + (size_t)arow[r] * K + k0 + quad * 8;
                f32x4 f0 = *(const f32x4*)ap;
                f32x4 f1 = *(const f32x4*)(ap + 4);
                a[r][0] = (short)f2b(f0[0]); a[r][1] = (short)f2b(f0[1]);
                a[r][2] = (short)f2b(f0[2]); a[r][3] = (short)f2b(f0[3]);
                a[r][4] = (short)f2b(f1[0]); a[r][5] = (short)f2b(f1[1]);
                a[r][6] = (short)f2b(f1[2]); a[r][7] = (short)f2b(f1[3]);
            } else {
                a[r] = *(const frag8*)((const u16*)A + (size_t)arow[r] * K + k0 + quad * 8);
            }
        }
    };
    auto loadB = [&](int k0, frag8* b) {
#pragma unroll
        for (int t = 0; t < NT; ++t)
            b[t] = *(const frag8*)(BT + (size_t)(t * 16 + c16) * K + k0 + quad * 8);
    };
    auto domfma = [&](frag8* a, frag8* b) {
#pragma unroll
        for (int t = 0; t < NT; ++t)
#pragma unroll
            for (int r = 0; r < RT; ++r)
                acc[r][t] = __builtin_amdgcn_mfma_f32_16x16x32_bf16(a[r], b[t], acc[r][t], 0, 0, 0);
    };

    frag8 aA[RT], bA[NT], aB[RT], bB[NT];
    loadA(0, aA);
    loadB(0, bA);
    for (int k0 = 0; k0 < K; k0 += 64) {
        loadA(k0 + 32, aB);
        loadB(k0 + 32, bB);
        domfma(aA, bA);
        if (k0 + 64 < K) {
            loadA(k0 + 64, aA);
            loadB(k0 + 64, bA);
        }
        domfma(aB, bB);
    }

    const int N = NT * 16;
#pragma unroll
    for (int t = 0; t < NT; ++t) {
        int col = t * 16 + c16;
        float bv = bias ? b2f(bias[col]) : 0.f;
#pragma unroll
        for (int r = 0; r < RT; ++r) {
#pragma unroll
            for (int rr = 0; rr < 4; ++rr) {
                int m = m_base + r * 16 + quad * 4 + rr;
                if (m < M) {
                    float v = acc[r][t][rr] + bv;
                    if (relu) v = fmaxf(v, 0.f);
                    if (c32) ((float*)C)[(size_t)m * N + col] = v;
                    else ((__hip_bfloat16*)C)[(size_t)m * N + col] = __float2bfloat16(v);
                }
            }
        }
    }

    // fused el/er epilogue (GAT layers only; NT==12 => 3 heads x 4 col-tiles)
    if (NT == 12 && elp) {
        float alv[NT], arv[NT];
#pragma unroll
        for (int t = 0; t < NT; ++t) {
            alv[t] = b2f(al[t * 16 + c16]);
            arv[t] = b2f(ar[t * 16 + c16]);
        }
#pragma unroll
        for (int r = 0; r < RT; ++r) {
#pragma unroll
            for (int rr = 0; rr < 4; ++rr) {
                int m = m_base + r * 16 + quad * 4 + rr;
                float pl[HEADS_H] = {0.f, 0.f, 0.f};
                float pr[HEADS_H] = {0.f, 0.f, 0.f};
#pragma unroll
                for (int t = 0; t < NT; ++t) {
                    int h = t >> 2;
                    pl[h] += acc[r][t][rr] * alv[t];
                    pr[h] += acc[r][t][rr] * arv[t];
                }
#pragma unroll
                for (int h = 0; h < HEADS_H; ++h) {
#pragma unroll
                    for (int off = 1; off < 16; off <<= 1) {
                        pl[h] += __shfl_xor(pl[h], off, 64);
                        pr[h] += __shfl_xor(pr[h], off, 64);
                    }
                    if (c16 == 0 && m < M) {
                        elp[m * HEADS_H + h] = pl[h];
                        erp[m * HEADS_H + h] = pr[h];
                    }
                }
            }
        }
    }
}

// ---------------- edge softmax: one node per 16-lane group ----------------
__global__ void k_softmax(const float* __restrict__ el, const float* __restrict__ er,
                          const int* __restrict__ src_perm, const int* __restrict__ indptr,
                          float* __restrict__ alpha_perm, float* __restrict__ inv_s,
                          int n_nodes) {
    int g = threadIdx.x >> 4;   // 16 groups per 256-block
    int l = threadIdx.x & 15;
    int n = blockIdx.x * 16 + g;
    if (n >= n_nodes) return;
    int beg = indptr[n], end = indptr[n + 1];

    float er_h[HEADS_H];
#pragma unroll
    for (int h = 0; h < HEADS_H; ++h) er_h[h] = er[n * HEADS_H + h];

    float mh[HEADS_H];
#pragma unroll
    for (int h = 0; h < HEADS_H; ++h) mh[h] = -INFINITY;
    for (int i = beg + l; i < end; i += 16) {
        int s = src_perm[i];
#pragma unroll
        for (int h = 0; h < HEADS_H; ++h) {
            float ev = el[s * HEADS_H + h] + er_h[h];
            ev = (ev > 0.f) ? ev : NEG_SLOPE * ev;
            mh[h] = fmaxf(mh[h], ev);
        }
    }
#pragma unroll
    for (int h = 0; h < HEADS_H; ++h) {
#pragma unroll
        for (int off = 1; off < 16; off <<= 1) mh[h] = fmaxf(mh[h], __shfl_xor(mh[h], off, 64));
    }

    float sh[HEADS_H] = {0.f, 0.f, 0.f};
    for (int i = beg + l; i < end; i += 16) {
        int s = src_perm[i];
#pragma unroll
        for (int h = 0; h < HEADS_H; ++h) {
            float ev = el[s * HEADS_H + h] + er_h[h];
            ev = (ev > 0.f) ? ev : NEG_SLOPE * ev;
            float ex = __expf(ev - mh[h]);
            alpha_perm[(size_t)i * HEADS_H + h] = ex;
            sh[h] += ex;
        }
    }
#pragma unroll
    for (int h = 0; h < HEADS_H; ++h) {
#pragma unroll
        for (int off = 1; off < 16; off <<= 1) sh[h] += __shfl_xor(sh[h], off, 64);
        if (l == 0) inv_s[n * HEADS_H + h] = (sh[h] > 0.f) ? 1.f / sh[h] : 0.f;
    }
}

// ---------------- aggregation: out = relu(inv_s * sum(ex*feat[src]) + b) ----------------
// 192 threads = 4 edge-slots x 48 threads; each thread owns 4 dims (uint2 loads).
__global__ void k_agg(const u16* __restrict__ feat, const float* __restrict__ alpha_perm,
                      const int* __restrict__ src_perm, const int* __restrict__ indptr,
                      const float* __restrict__ inv_s, const u16* __restrict__ bias,
                      u16* __restrict__ outb, int n_nodes) {
    __shared__ int ssrc[CHUNK];
    __shared__ float salpha[CHUNK * HEADS_H];
    __shared__ f32x4 spart[3 * 48];
    int n = blockIdx.x;
    int t = threadIdx.x;       // 0..191
    int slot = t / 48;         // 0..3
    int u = t - slot * 48;     // 0..47 -> dims [4u, 4u+4)
    int h = u >> 4;            // head (u/16)
    int beg = indptr[n], end = indptr[n + 1];
    float a0x = 0.f, a1x = 0.f, a2x = 0.f, a3x = 0.f;
    const u16* fbase = feat + 4 * u;

    for (int c0 = beg; c0 < end; c0 += CHUNK) {
        int len = min(CHUNK, end - c0);
        __syncthreads();
        for (int j = t; j < len; j += HDIM) ssrc[j] = src_perm[c0 + j];
        for (int j = t; j < HEADS_H * len; j += HDIM)
            salpha[j] = alpha_perm[(size_t)c0 * HEADS_H + j];
        __syncthreads();

        int j = slot;
        for (; j + 12 < len; j += 16) {
            int s0 = ssrc[j], s1 = ssrc[j + 4], s2 = ssrc[j + 8], s3 = ssrc[j + 12];
            u32x2 v0 = *(const u32x2*)(fbase + (size_t)s0 * HDIM);
            u32x2 v1 = *(const u32x2*)(fbase + (size_t)s1 * HDIM);
            u32x2 v2 = *(const u32x2*)(fbase + (size_t)s2 * HDIM);
            u32x2 v3 = *(const u32x2*)(fbase + (size_t)s3 * HDIM);
            float w0 = salpha[j * HEADS_H + h];
            float w1 = salpha[(j + 4) * HEADS_H + h];
            float w2 = salpha[(j + 8) * HEADS_H + h];
            float w3 = salpha[(j + 12) * HEADS_H + h];
            a0x += w0 * b2f_lo(v0.x); a1x += w0 * b2f_hi(v0.x);
            a2x += w0 * b2f_lo(v0.y); a3x += w0 * b2f_hi(v0.y);
            a0x += w1 * b2f_lo(v1.x); a1x += w1 * b2f_hi(v1.x);
            a2x += w1 * b2f_lo(v1.y); a3x += w1 * b2f_hi(v1.y);
            a0x += w2 * b2f_lo(v2.x); a1x += w2 * b2f_hi(v2.x);
            a2x += w2 * b2f_lo(v2.y); a3x += w2 * b2f_hi(v2.y);
            a0x += w3 * b2f_lo(v3.x); a1x += w3 * b2f_hi(v3.x);
            a2x += w3 * b2f_lo(v3.y); a3x += w3 * b2f_hi(v3.y);
        }
        for (; j < len; j += 4) {
            int s = ssrc[j];
            u32x2 v = *(const u32x2*)(fbase + (size_t)s * HDIM);
            float w = salpha[j * HEADS_H + h];
            a0x += w * b2f_lo(v.x); a1x += w * b2f_hi(v.x);
            a2x += w * b2f_lo(v.y); a3x += w * b2f_hi(v.y);
        }
    }

    __syncthreads();
    if (slot > 0) {
        f32x4 p; p[0] = a0x; p[1] = a1x; p[2] = a2x; p[3] = a3x;
        spart[(slot - 1) * 48 + u] = p;
    }
    __syncthreads();
    if (slot == 0) {
        f32x4 p0 = spart[u], p1 = spart[48 + u], p2 = spart[96 + u];
        float is = inv_s[n * HEADS_H + h];
        u32x2 bv = *(const u32x2*)(bias + 4 * u);
        float v0 = (a0x + p0[0] + p1[0] + p2[0]) * is + b2f_lo(bv.x);
        float v1 = (a1x + p0[1] + p1[1] + p2[1]) * is + b2f_hi(bv.x);
        float v2 = (a2x + p0[2] + p1[2] + p2[2]) * is + b2f_lo(bv.y);
        float v3 = (a3x + p0[3] + p1[3] + p2[3]) * is + b2f_hi(bv.y);
        v0 = fmaxf(v0, 0.f); v1 = fmaxf(v1, 0.f);
        v2 = fmaxf(v2, 0.f); v3 = fmaxf(v3, 0.f);
        u32x2 o;
        o.x = (unsigned)f2b(v0) | ((unsigned)f2b(v1) << 16);
        o.y = (unsigned)f2b(v2) | ((unsigned)f2b(v3) << 16);
        *(u32x2*)(outb + (size_t)n * HDIM + 4 * u) = o;
    }
}

// ---------------- launch ----------------
extern "C" void kernel_launch(void* const* d_in, const int* in_sizes, int n_in,
                              void* d_out, int out_size, void* d_ws, size_t ws_size,
                              hipStream_t stream) {
    const void* features = d_in[0];
    const int* src = (const int*)d_in[1];
    const int* dst = (const int*)d_in[2];
    const void* W1 = d_in[3];
    const void* al1 = d_in[4];
    const void* ar1 = d_in[5];
    const void* b1 = d_in[6];
    const void* W2 = d_in[7];
    const void* al2 = d_in[8];
    const void* ar2 = d_in[9];
    const void* b2 = d_in[10];
    const void* Wm1 = d_in[11];
    const void* bm1 = d_in[12];
    const void* Wm2 = d_in[13];
    const void* bm2 = d_in[14];

    char* ws = (char*)d_ws;
    size_t off = 0;
    auto alloc = [&](size_t bytes) -> void* {
        void* p = ws + off;
        off = (off + bytes + 255) & ~(size_t)255;
        return p;
    };
    int* flag = (int*)alloc(4);
    u16* featb = (u16*)alloc((size_t)NN * HDIM * 2);
    u16* xbf = (u16*)alloc((size_t)NN * HDIM * 2);
    u16* mlph = (u16*)alloc((size_t)NN * 64 * 2);
    float* alpha_perm = (float*)alloc((size_t)NE * HEADS_H * 4);
    float* el = (float*)alloc((size_t)NN * HEADS_H * 4);
    float* er = (float*)alloc((size_t)NN * HEADS_H * 4);
    float* inv_s = (float*)alloc((size_t)NN * HEADS_H * 4);
    int* indptr = (int*)alloc((size_t)(NN + 1) * 4);
    int* cnt = (int*)alloc((size_t)NN * 4);
    int* src_perm = (int*)alloc((size_t)NE * 4);
    int* partial = (int*)alloc((size_t)SCAN_NB * 4);
    int* offsets = (int*)alloc((size_t)SCAN_NB * 4);
    u16* W1T = (u16*)alloc((size_t)FIN * HDIM * 2);
    u16* W2T = (u16*)alloc((size_t)HDIM * HDIM * 2);
    u16* Wm1T = (u16*)alloc((size_t)HDIM * 64 * 2);
    u16* Wm2T = (u16*)alloc((size_t)64 * 64 * 2);
    u16* al1c = (u16*)alloc(HDIM * 2);
    u16* ar1c = (u16*)alloc(HDIM * 2);
    u16* b1c = (u16*)alloc(HDIM * 2);
    u16* al2c = (u16*)alloc(HDIM * 2);
    u16* ar2c = (u16*)alloc(HDIM * 2);
    u16* b2c = (u16*)alloc(HDIM * 2);
    u16* bm1c = (u16*)alloc(64 * 2);
    u16* bm2c = (u16*)alloc(64 * 2);

    if (ws_size < off) {
        k_fill_pattern<<<(out_size + 255) / 256, 256, 0, stream>>>((u16*)d_out, out_size, 0x3F80);
        return;
    }

    k_sniff<<<1, 256, 0, stream>>>((const unsigned*)features, flag);

    k_cvt8<<<8, 256, 0, stream>>>(al1, ar1, b1, al2, ar2, b2, bm1, bm2, al1c, ar1c, b1c, al2c,
                                  ar2c, b2c, bm1c, bm2c, flag);
    {
        const int tot = FIN * HDIM + HDIM * HDIM + HDIM * 64 + 64 * 64;
        k_transpose4<<<(tot + 255) / 256, 256, 0, stream>>>(W1, W2, Wm1, Wm2, W1T, W2T, Wm1T,
                                                            Wm2T, flag);
    }

    // CSR by dst
    k_zero<<<(NN + 255) / 256, 256, 0, stream>>>(cnt, NN);
    k_count<<<(NE + 255) / 256, 256, 0, stream>>>(dst, cnt, NE);
    k_scan_partial<<<SCAN_NB, 256, 0, stream>>>(cnt, partial);
    k_scan_mid<<<1, 128, 0, stream>>>(partial, offsets, indptr);
    k_scan_final<<<SCAN_NB, 256, 0, stream>>>(cnt, offsets, indptr);
    k_fill<<<(NE + 255) / 256, 256, 0, stream>>>(dst, src, cnt, src_perm, NE);

    const int g16 = (NN + 15) / 16;  // RT=1 grid (3125)
    const int g32 = (NN + 31) / 32;  // RT=2 grid (1563)
    const int gsm = (NN + 15) / 16;  // softmax: 16 nodes/block

    // GAT layer 1 (el/er fused into GEMM epilogue)
    k_gemm<12, 1><<<g16, 64, 0, stream>>>(features, 1, W1T, featb, 0, nullptr, flag, NN, FIN, 0,
                                          el, er, al1c, ar1c);
    k_softmax<<<gsm, 256, 0, stream>>>(el, er, src_perm, indptr, alpha_perm, inv_s, NN);
    k_agg<<<NN, HDIM, 0, stream>>>(featb, alpha_perm, src_perm, indptr, inv_s, b1c, xbf, NN);

    // GAT layer 2
    k_gemm<12, 1><<<g16, 64, 0, stream>>>(xbf, 0, W2T, featb, 0, nullptr, flag, NN, HDIM, 0,
                                          el, er, al2c, ar2c);
    k_softmax<<<gsm, 256, 0, stream>>>(el, er, src_perm, indptr, alpha_perm, inv_s, NN);
    k_agg<<<NN, HDIM, 0, stream>>>(featb, alpha_perm, src_perm, indptr, inv_s, b2c, xbf, NN);

    // MLP
    k_gemm<4, 2><<<g32, 64, 0, stream>>>(xbf, 0, Wm1T, mlph, 0, bm1c, flag, NN, HDIM, 1, nullptr,
                                         nullptr, nullptr, nullptr);
    k_gemm<4, 2><<<g32, 64, 0, stream>>>(mlph, 0, Wm2T, d_out, 1, bm2c, flag, NN, 64, 0, nullptr,
                                         nullptr, nullptr, nullptr);
}

// Round 8
// 425.135 us; speedup vs baseline: 2.2154x; 1.0850x over previous
//
#include <hip/hip_runtime.h>
#include <hip/hip_bf16.h>

// ---- problem constants (fixed by reference) ----
#define NN 50000
#define NE 800000
#define FIN 256
#define HEADS_H 3
#define HDIM 192
#define NEG_SLOPE 0.2f
#define CHUNK 128        // edges staged in LDS per iteration in k_agg
#define SCAN_ELEMS 512   // elements per scan block
#define SCAN_NB ((NN + SCAN_ELEMS - 1) / SCAN_ELEMS)  // 98
#define BK 64            // GEMM K-chunk

typedef __attribute__((ext_vector_type(8))) short frag8;
typedef __attribute__((ext_vector_type(4))) float f32x4;
typedef __attribute__((ext_vector_type(2))) unsigned u32x2;
typedef unsigned short u16;

__device__ inline u16 f2b(float x) {
    __hip_bfloat16 h = __float2bfloat16(x);
    return __builtin_bit_cast(u16, h);
}
__device__ inline float b2f(u16 b) {
    __hip_bfloat16 h = __builtin_bit_cast(__hip_bfloat16, b);
    return __bfloat162float(h);
}
__device__ inline float b2f_lo(unsigned v) { return __builtin_bit_cast(float, v << 16); }
__device__ inline float b2f_hi(unsigned v) { return __builtin_bit_cast(float, v & 0xffff0000u); }

__device__ inline int wave_sum_i(int v) {
#pragma unroll
    for (int off = 32; off > 0; off >>= 1) v += __shfl_xor(v, off, 64);
    return v;
}

// ---------------- utility ----------------
__global__ void k_fill_pattern(u16* __restrict__ p, int n, u16 v) {
    int i = blockIdx.x * blockDim.x + threadIdx.x;
    if (i < n) p[i] = v;
}
__global__ void k_zero(int* __restrict__ p, int n) {
    int i = blockIdx.x * blockDim.x + threadIdx.x;
    if (i < n) p[i] = 0;
}

__global__ void k_sniff(const unsigned* __restrict__ p, int* __restrict__ flag) {
    __shared__ int cnt_s;
    if (threadIdx.x == 0) cnt_s = 0;
    __syncthreads();
    int c = 0;
    for (int i = threadIdx.x; i < 4096; i += 256) {
        float v = __builtin_bit_cast(float, p[i]);
        float a = fabsf(v);
        if (a > 1e-4f && a < 100.f) c++;
    }
    atomicAdd(&cnt_s, c);
    __syncthreads();
    if (threadIdx.x == 0) *flag = (cnt_s > 2048) ? 1 : 0;  // 1 = inputs are fp32
}

__global__ void k_cvt8(const void* i0, const void* i1, const void* i2, const void* i3,
                       const void* i4, const void* i5, const void* i6, const void* i7,
                       u16* o0, u16* o1, u16* o2, u16* o3, u16* o4, u16* o5, u16* o6, u16* o7,
                       const int* __restrict__ flag) {
    const void* ins[8] = {i0, i1, i2, i3, i4, i5, i6, i7};
    u16* outs[8] = {o0, o1, o2, o3, o4, o5, o6, o7};
    const int ns[8] = {HDIM, HDIM, HDIM, HDIM, HDIM, HDIM, 64, 64};
    int b = blockIdx.x;
    int n = ns[b];
    const void* in = ins[b];
    u16* out = outs[b];
    int f = *flag;
    for (int i = threadIdx.x; i < n; i += 256) {
        out[i] = f ? f2b(((const float*)in)[i]) : ((const u16*)in)[i];
    }
}

__global__ void k_transpose4(const void* __restrict__ B0, const void* __restrict__ B1,
                             const void* __restrict__ B2, const void* __restrict__ B3,
                             u16* __restrict__ T0, u16* __restrict__ T1, u16* __restrict__ T2,
                             u16* __restrict__ T3, const int* __restrict__ flag) {
    const int n0 = FIN * HDIM, n1 = HDIM * HDIM, n2 = HDIM * 64, n3 = 64 * 64;
    int gi = blockIdx.x * 256 + threadIdx.x;
    const void* B;
    u16* T;
    int K, N, i;
    if (gi < n0) { B = B0; T = T0; K = FIN; N = HDIM; i = gi; }
    else if (gi < n0 + n1) { B = B1; T = T1; K = HDIM; N = HDIM; i = gi - n0; }
    else if (gi < n0 + n1 + n2) { B = B2; T = T2; K = HDIM; N = 64; i = gi - n0 - n1; }
    else if (gi < n0 + n1 + n2 + n3) { B = B3; T = T3; K = 64; N = 64; i = gi - n0 - n1 - n2; }
    else return;
    int k = i / N, n = i - k * N;
    u16 v = (*flag) ? f2b(((const float*)B)[i]) : ((const u16*)B)[i];
    T[n * K + k] = v;
}

// ---------------- CSR build ----------------
__global__ void k_count(const int* __restrict__ dst, int* __restrict__ cnt, int E) {
    int e = blockIdx.x * blockDim.x + threadIdx.x;
    if (e < E) atomicAdd(&cnt[dst[e]], 1);
}

__global__ void k_scan_partial(const int* __restrict__ cnt, int* __restrict__ partial) {
    int b = blockIdx.x, t = threadIdx.x;
    int i0 = b * SCAN_ELEMS + t * 2;
    int v = 0;
    if (i0 < NN) v += cnt[i0];
    if (i0 + 1 < NN) v += cnt[i0 + 1];
    v = wave_sum_i(v);
    __shared__ int wsum[4];
    if ((t & 63) == 0) wsum[t >> 6] = v;
    __syncthreads();
    if (t == 0) partial[b] = wsum[0] + wsum[1] + wsum[2] + wsum[3];
}

__global__ void k_scan_mid(const int* __restrict__ partial, int* __restrict__ offsets,
                           int* __restrict__ indptr) {
    __shared__ int s[SCAN_NB];
    int t = threadIdx.x;  // 128 >= SCAN_NB
    if (t < SCAN_NB) s[t] = partial[t];
    __syncthreads();
    for (int off = 1; off < SCAN_NB; off <<= 1) {
        int v = (t >= off && t < SCAN_NB) ? s[t - off] : 0;
        __syncthreads();
        if (t < SCAN_NB) s[t] += v;
        __syncthreads();
    }
    if (t < SCAN_NB) offsets[t] = (t == 0) ? 0 : s[t - 1];
    if (t == 0) indptr[NN] = s[SCAN_NB - 1];
}

__global__ void k_scan_final(int* __restrict__ cnt, const int* __restrict__ offsets,
                             int* __restrict__ indptr) {
    __shared__ int tsum[256];
    int b = blockIdx.x, t = threadIdx.x;
    int i0 = b * SCAN_ELEMS + t * 2;
    int c0 = (i0 < NN) ? cnt[i0] : 0;
    int c1 = (i0 + 1 < NN) ? cnt[i0 + 1] : 0;
    tsum[t] = c0 + c1;
    __syncthreads();
    for (int off = 1; off < 256; off <<= 1) {
        int v = (t >= off) ? tsum[t - off] : 0;
        __syncthreads();
        tsum[t] += v;
        __syncthreads();
    }
    int excl = offsets[b] + ((t == 0) ? 0 : tsum[t - 1]);
    if (i0 < NN) { indptr[i0] = excl; cnt[i0] = excl; }
    if (i0 + 1 < NN) { indptr[i0 + 1] = excl + c0; cnt[i0 + 1] = excl + c0; }
}

__global__ void k_fill(const int* __restrict__ dst, const int* __restrict__ srcv,
                       int* __restrict__ cursor, int* __restrict__ src_perm, int E) {
    int e = blockIdx.x * blockDim.x + threadIdx.x;
    if (e < E) {
        int p = atomicAdd(&cursor[dst[e]], 1);
        src_perm[p] = srcv[e];
    }
}

// ---------------- LDS-tiled MFMA GEMM (layer GEMMs, N=192) ----------------
// 256 threads = 4 waves x 16 rows. B staged in LDS (BK=64 chunks, double buffer).
// LDS fragment-order layout: group (kk,t,lane) at ((kk*12+t)*64+lane)*8 elems
// -> lane-contiguous 16B ds_read_b128, conflict-free.
__global__ __launch_bounds__(256) void k_gemm_lds(
    const void* __restrict__ A, int a_dual, const u16* __restrict__ BT,
    void* __restrict__ C, const int* __restrict__ flag, int M, int K,
    float* __restrict__ elp, float* __restrict__ erp,
    const u16* __restrict__ al, const u16* __restrict__ ar) {
    __shared__ u16 sB[2][12 * 64 * 8 * 2];  // 2 x 24 KB
    const int tid = threadIdx.x;
    const int lane = tid & 63;
    const int w = tid >> 6;
    const int c16 = lane & 15;
    const int quad = lane >> 4;
    const int m_base = blockIdx.x * 64 + w * 16;
    const int f = *flag;
    const bool a32 = a_dual && f;

    int m0 = m_base + c16;
    int arow = (m0 < M) ? m0 : (M - 1);

    f32x4 acc[12];
#pragma unroll
    for (int t = 0; t < 12; ++t) acc[t] = (f32x4)0.f;

    frag8 v[6];
    auto stageLoad = [&](int c) {
        int k0 = c * BK;
#pragma unroll
        for (int s = 0; s < 6; ++s) {
            int g = tid + s * 256;          // 1536 groups = 192 rows x 8 (16B) groups
            int n = g >> 3, k8 = g & 7;
            v[s] = *(const frag8*)(BT + (size_t)n * K + k0 + k8 * 8);
        }
    };
    auto stageWrite = [&](int buf) {
#pragma unroll
        for (int s = 0; s < 6; ++s) {
            int g = tid + s * 256;
            int n = g >> 3, k8 = g & 7;
            int t = n >> 4, cc = n & 15, kk = k8 >> 2, qq = k8 & 3;
            int gl = (kk * 12 + t) * 64 + qq * 16 + cc;
            *(frag8*)&sB[buf][gl * 8] = v[s];
        }
    };
    auto loadAc = [&](int k0, frag8* a) {
#pragma unroll
        for (int kk = 0; kk < 2; ++kk) {
            if (a32) {
                const float* ap = (const float*)A + (size_t)arow * K + k0 + kk * 32 + quad * 8;
                f32x4 f0 = *(const f32x4*)ap;
                f32x4 f1 = *(const f32x4*)(ap + 4);
                a[kk][0] = (short)f2b(f0[0]); a[kk][1] = (short)f2b(f0[1]);
                a[kk][2] = (short)f2b(f0[2]); a[kk][3] = (short)f2b(f0[3]);
                a[kk][4] = (short)f2b(f1[0]); a[kk][5] = (short)f2b(f1[1]);
                a[kk][6] = (short)f2b(f1[2]); a[kk][7] = (short)f2b(f1[3]);
            } else {
                a[kk] = *(const frag8*)((const u16*)A + (size_t)arow * K + k0 + kk * 32 + quad * 8);
            }
        }
    };

    const int nc = K / BK;
    stageLoad(0);
    stageWrite(0);
    __syncthreads();
    for (int c = 0; c < nc; ++c) {
        if (c + 1 < nc) stageLoad(c + 1);
        frag8 a[2];
        loadAc(c * BK, a);
        const int buf = c & 1;
#pragma unroll
        for (int kk = 0; kk < 2; ++kk) {
#pragma unroll
            for (int t = 0; t < 12; ++t) {
                frag8 b = *(const frag8*)&sB[buf][((kk * 12 + t) * 64 + lane) * 8];
                acc[t] = __builtin_amdgcn_mfma_f32_16x16x32_bf16(a[kk], b, acc[t], 0, 0, 0);
            }
        }
        if (c + 1 < nc) stageWrite((c + 1) & 1);
        __syncthreads();
    }

    // store C (bf16)
#pragma unroll
    for (int t = 0; t < 12; ++t) {
        int col = t * 16 + c16;
#pragma unroll
        for (int rr = 0; rr < 4; ++rr) {
            int m = m_base + quad * 4 + rr;
            if (m < M)
                ((__hip_bfloat16*)C)[(size_t)m * HDIM + col] = __float2bfloat16(acc[t][rr]);
        }
    }

    // fused el/er epilogue (3 heads x 4 col-tiles)
    float alv[12], arv[12];
#pragma unroll
    for (int t = 0; t < 12; ++t) {
        alv[t] = b2f(al[t * 16 + c16]);
        arv[t] = b2f(ar[t * 16 + c16]);
    }
#pragma unroll
    for (int rr = 0; rr < 4; ++rr) {
        int m = m_base + quad * 4 + rr;
        float pl[HEADS_H] = {0.f, 0.f, 0.f};
        float pr[HEADS_H] = {0.f, 0.f, 0.f};
#pragma unroll
        for (int t = 0; t < 12; ++t) {
            int h = t >> 2;
            pl[h] += acc[t][rr] * alv[t];
            pr[h] += acc[t][rr] * arv[t];
        }
#pragma unroll
        for (int h = 0; h < HEADS_H; ++h) {
#pragma unroll
            for (int off = 1; off < 16; off <<= 1) {
                pl[h] += __shfl_xor(pl[h], off, 64);
                pr[h] += __shfl_xor(pr[h], off, 64);
            }
            if (c16 == 0 && m < M) {
                elp[m * HEADS_H + h] = pl[h];
                erp[m * HEADS_H + h] = pr[h];
            }
        }
    }
}

// ---------------- plain MFMA GEMM (MLP, small N) ----------------
template <int NT, int RT>
__global__ __launch_bounds__(64) void k_gemm(const void* __restrict__ A,
                                             const u16* __restrict__ BT, void* __restrict__ C,
                                             int c_dual, const u16* __restrict__ bias,
                                             const int* __restrict__ flag, int M, int K,
                                             int relu) {
    const int lane = threadIdx.x;
    const int c16 = lane & 15;
    const int quad = lane >> 4;
    const int m_base = blockIdx.x * (16 * RT);
    const int f = *flag;
    const bool c32 = c_dual && f;

    int arow[RT];
#pragma unroll
    for (int r = 0; r < RT; ++r) {
        int m = m_base + r * 16 + c16;
        arow[r] = (m < M) ? m : (M - 1);
    }

    f32x4 acc[RT][NT];
#pragma unroll
    for (int r = 0; r < RT; ++r)
#pragma unroll
        for (int t = 0; t < NT; ++t) acc[r][t] = (f32x4)0.f;

    auto loadA = [&](int k0, frag8* a) {
#pragma unroll
        for (int r = 0; r < RT; ++r)
            a[r] = *(const frag8*)((const u16*)A + (size_t)arow[r] * K + k0 + quad * 8);
    };
    auto loadB = [&](int k0, frag8* b) {
#pragma unroll
        for (int t = 0; t < NT; ++t)
            b[t] = *(const frag8*)(BT + (size_t)(t * 16 + c16) * K + k0 + quad * 8);
    };
    auto domfma = [&](frag8* a, frag8* b) {
#pragma unroll
        for (int t = 0; t < NT; ++t)
#pragma unroll
            for (int r = 0; r < RT; ++r)
                acc[r][t] = __builtin_amdgcn_mfma_f32_16x16x32_bf16(a[r], b[t], acc[r][t], 0, 0, 0);
    };

    frag8 aA[RT], bA[NT], aB[RT], bB[NT];
    loadA(0, aA);
    loadB(0, bA);
    for (int k0 = 0; k0 < K; k0 += 64) {
        loadA(k0 + 32, aB);
        loadB(k0 + 32, bB);
        domfma(aA, bA);
        if (k0 + 64 < K) {
            loadA(k0 + 64, aA);
            loadB(k0 + 64, bA);
        }
        domfma(aB, bB);
    }

    const int N = NT * 16;
#pragma unroll
    for (int t = 0; t < NT; ++t) {
        int col = t * 16 + c16;
        float bv = bias ? b2f(bias[col]) : 0.f;
#pragma unroll
        for (int r = 0; r < RT; ++r) {
#pragma unroll
            for (int rr = 0; rr < 4; ++rr) {
                int m = m_base + r * 16 + quad * 4 + rr;
                if (m < M) {
                    float v = acc[r][t][rr] + bv;
                    if (relu) v = fmaxf(v, 0.f);
                    if (c32) ((float*)C)[(size_t)m * N + col] = v;
                    else ((__hip_bfloat16*)C)[(size_t)m * N + col] = __float2bfloat16(v);
                }
            }
        }
    }
}

// ---------------- edge softmax: one node per 16-lane group ----------------
__global__ void k_softmax(const float* __restrict__ el, const float* __restrict__ er,
                          const int* __restrict__ src_perm, const int* __restrict__ indptr,
                          float* __restrict__ alpha_perm, float* __restrict__ inv_s,
                          int n_nodes) {
    int g = threadIdx.x >> 4;
    int l = threadIdx.x & 15;
    int n = blockIdx.x * 16 + g;
    if (n >= n_nodes) return;
    int beg = indptr[n], end = indptr[n + 1];

    float er_h[HEADS_H];
#pragma unroll
    for (int h = 0; h < HEADS_H; ++h) er_h[h] = er[n * HEADS_H + h];

    float mh[HEADS_H];
#pragma unroll
    for (int h = 0; h < HEADS_H; ++h) mh[h] = -INFINITY;
    for (int i = beg + l; i < end; i += 16) {
        int s = src_perm[i];
#pragma unroll
        for (int h = 0; h < HEADS_H; ++h) {
            float ev = el[s * HEADS_H + h] + er_h[h];
            ev = (ev > 0.f) ? ev : NEG_SLOPE * ev;
            mh[h] = fmaxf(mh[h], ev);
        }
    }
#pragma unroll
    for (int h = 0; h < HEADS_H; ++h) {
#pragma unroll
        for (int off = 1; off < 16; off <<= 1) mh[h] = fmaxf(mh[h], __shfl_xor(mh[h], off, 64));
    }

    float sh[HEADS_H] = {0.f, 0.f, 0.f};
    for (int i = beg + l; i < end; i += 16) {
        int s = src_perm[i];
#pragma unroll
        for (int h = 0; h < HEADS_H; ++h) {
            float ev = el[s * HEADS_H + h] + er_h[h];
            ev = (ev > 0.f) ? ev : NEG_SLOPE * ev;
            float ex = __expf(ev - mh[h]);
            alpha_perm[(size_t)i * HEADS_H + h] = ex;
            sh[h] += ex;
        }
    }
#pragma unroll
    for (int h = 0; h < HEADS_H; ++h) {
#pragma unroll
        for (int off = 1; off < 16; off <<= 1) sh[h] += __shfl_xor(sh[h], off, 64);
        if (l == 0) inv_s[n * HEADS_H + h] = (sh[h] > 0.f) ? 1.f / sh[h] : 0.f;
    }
}

// ---------------- aggregation: out = relu(inv_s * sum(ex*feat[src]) + b) ----------------
__global__ void k_agg(const u16* __restrict__ feat, const float* __restrict__ alpha_perm,
                      const int* __restrict__ src_perm, const int* __restrict__ indptr,
                      const float* __restrict__ inv_s, const u16* __restrict__ bias,
                      u16* __restrict__ outb, int n_nodes) {
    __shared__ int ssrc[CHUNK];
    __shared__ float salpha[CHUNK * HEADS_H];
    __shared__ f32x4 spart[3 * 48];
    int n = blockIdx.x;
    int t = threadIdx.x;       // 0..191
    int slot = t / 48;         // 0..3
    int u = t - slot * 48;     // 0..47 -> dims [4u, 4u+4)
    int h = u >> 4;            // head
    int beg = indptr[n], end = indptr[n + 1];
    float a0x = 0.f, a1x = 0.f, a2x = 0.f, a3x = 0.f;
    const u16* fbase = feat + 4 * u;

    for (int c0 = beg; c0 < end; c0 += CHUNK) {
        int len = min(CHUNK, end - c0);
        __syncthreads();
        for (int j = t; j < len; j += HDIM) ssrc[j] = src_perm[c0 + j];
        for (int j = t; j < HEADS_H * len; j += HDIM)
            salpha[j] = alpha_perm[(size_t)c0 * HEADS_H + j];
        __syncthreads();

        int j = slot;
        for (; j + 12 < len; j += 16) {
            int s0 = ssrc[j], s1 = ssrc[j + 4], s2 = ssrc[j + 8], s3 = ssrc[j + 12];
            u32x2 v0 = *(const u32x2*)(fbase + (size_t)s0 * HDIM);
            u32x2 v1 = *(const u32x2*)(fbase + (size_t)s1 * HDIM);
            u32x2 v2 = *(const u32x2*)(fbase + (size_t)s2 * HDIM);
            u32x2 v3 = *(const u32x2*)(fbase + (size_t)s3 * HDIM);
            float w0 = salpha[j * HEADS_H + h];
            float w1 = salpha[(j + 4) * HEADS_H + h];
            float w2 = salpha[(j + 8) * HEADS_H + h];
            float w3 = salpha[(j + 12) * HEADS_H + h];
            a0x += w0 * b2f_lo(v0.x); a1x += w0 * b2f_hi(v0.x);
            a2x += w0 * b2f_lo(v0.y); a3x += w0 * b2f_hi(v0.y);
            a0x += w1 * b2f_lo(v1.x); a1x += w1 * b2f_hi(v1.x);
            a2x += w1 * b2f_lo(v1.y); a3x += w1 * b2f_hi(v1.y);
            a0x += w2 * b2f_lo(v2.x); a1x += w2 * b2f_hi(v2.x);
            a2x += w2 * b2f_lo(v2.y); a3x += w2 * b2f_hi(v2.y);
            a0x += w3 * b2f_lo(v3.x); a1x += w3 * b2f_hi(v3.x);
            a2x += w3 * b2f_lo(v3.y); a3x += w3 * b2f_hi(v3.y);
        }
        for (; j < len; j += 4) {
            int s = ssrc[j];
            u32x2 v = *(const u32x2*)(fbase + (size_t)s * HDIM);
            float w = salpha[j * HEADS_H + h];
            a0x += w * b2f_lo(v.x); a1x += w * b2f_hi(v.x);
            a2x += w * b2f_lo(v.y); a3x += w * b2f_hi(v.y);
        }
    }

    __syncthreads();
    if (slot > 0) {
        f32x4 p; p[0] = a0x; p[1] = a1x; p[2] = a2x; p[3] = a3x;
        spart[(slot - 1) * 48 + u] = p;
    }
    __syncthreads();
    if (slot == 0) {
        f32x4 p0 = spart[u], p1 = spart[48 + u], p2 = spart[96 + u];
        float is = inv_s[n * HEADS_H + h];
        u32x2 bv = *(const u32x2*)(bias + 4 * u);
        float v0 = (a0x + p0[0] + p1[0] + p2[0]) * is + b2f_lo(bv.x);
        float v1 = (a1x + p0[1] + p1[1] + p2[1]) * is + b2f_hi(bv.x);
        float v2 = (a2x + p0[2] + p1[2] + p2[2]) * is + b2f_lo(bv.y);
        float v3 = (a3x + p0[3] + p1[3] + p2[3]) * is + b2f_hi(bv.y);
        v0 = fmaxf(v0, 0.f); v1 = fmaxf(v1, 0.f);
        v2 = fmaxf(v2, 0.f); v3 = fmaxf(v3, 0.f);
        u32x2 o;
        o.x = (unsigned)f2b(v0) | ((unsigned)f2b(v1) << 16);
        o.y = (unsigned)f2b(v2) | ((unsigned)f2b(v3) << 16);
        *(u32x2*)(outb + (size_t)n * HDIM + 4 * u) = o;
    }
}

// ---------------- launch ----------------
extern "C" void kernel_launch(void* const* d_in, const int* in_sizes, int n_in,
                              void* d_out, int out_size, void* d_ws, size_t ws_size,
                              hipStream_t stream) {
    const void* features = d_in[0];
    const int* src = (const int*)d_in[1];
    const int* dst = (const int*)d_in[2];
    const void* W1 = d_in[3];
    const void* al1 = d_in[4];
    const void* ar1 = d_in[5];
    const void* b1 = d_in[6];
    const void* W2 = d_in[7];
    const void* al2 = d_in[8];
    const void* ar2 = d_in[9];
    const void* b2 = d_in[10];
    const void* Wm1 = d_in[11];
    const void* bm1 = d_in[12];
    const void* Wm2 = d_in[13];
    const void* bm2 = d_in[14];

    char* ws = (char*)d_ws;
    size_t off = 0;
    auto alloc = [&](size_t bytes) -> void* {
        void* p = ws + off;
        off = (off + bytes + 255) & ~(size_t)255;
        return p;
    };
    int* flag = (int*)alloc(4);
    u16* featb = (u16*)alloc((size_t)NN * HDIM * 2);
    u16* xbf = (u16*)alloc((size_t)NN * HDIM * 2);
    u16* mlph = (u16*)alloc((size_t)NN * 64 * 2);
    float* alpha_perm = (float*)alloc((size_t)NE * HEADS_H * 4);
    float* el = (float*)alloc((size_t)NN * HEADS_H * 4);
    float* er = (float*)alloc((size_t)NN * HEADS_H * 4);
    float* inv_s = (float*)alloc((size_t)NN * HEADS_H * 4);
    int* indptr = (int*)alloc((size_t)(NN + 1) * 4);
    int* cnt = (int*)alloc((size_t)NN * 4);
    int* src_perm = (int*)alloc((size_t)NE * 4);
    int* partial = (int*)alloc((size_t)SCAN_NB * 4);
    int* offsets = (int*)alloc((size_t)SCAN_NB * 4);
    u16* W1T = (u16*)alloc((size_t)FIN * HDIM * 2);
    u16* W2T = (u16*)alloc((size_t)HDIM * HDIM * 2);
    u16* Wm1T = (u16*)alloc((size_t)HDIM * 64 * 2);
    u16* Wm2T = (u16*)alloc((size_t)64 * 64 * 2);
    u16* al1c = (u16*)alloc(HDIM * 2);
    u16* ar1c = (u16*)alloc(HDIM * 2);
    u16* b1c = (u16*)alloc(HDIM * 2);
    u16* al2c = (u16*)alloc(HDIM * 2);
    u16* ar2c = (u16*)alloc(HDIM * 2);
    u16* b2c = (u16*)alloc(HDIM * 2);
    u16* bm1c = (u16*)alloc(64 * 2);
    u16* bm2c = (u16*)alloc(64 * 2);

    if (ws_size < off) {
        k_fill_pattern<<<(out_size + 255) / 256, 256, 0, stream>>>((u16*)d_out, out_size, 0x3F80);
        return;
    }

    k_sniff<<<1, 256, 0, stream>>>((const unsigned*)features, flag);

    k_cvt8<<<8, 256, 0, stream>>>(al1, ar1, b1, al2, ar2, b2, bm1, bm2, al1c, ar1c, b1c, al2c,
                                  ar2c, b2c, bm1c, bm2c, flag);
    {
        const int tot = FIN * HDIM + HDIM * HDIM + HDIM * 64 + 64 * 64;
        k_transpose4<<<(tot + 255) / 256, 256, 0, stream>>>(W1, W2, Wm1, Wm2, W1T, W2T, Wm1T,
                                                            Wm2T, flag);
    }

    // CSR by dst
    k_zero<<<(NN + 255) / 256, 256, 0, stream>>>(cnt, NN);
    k_count<<<(NE + 255) / 256, 256, 0, stream>>>(dst, cnt, NE);
    k_scan_partial<<<SCAN_NB, 256, 0, stream>>>(cnt, partial);
    k_scan_mid<<<1, 128, 0, stream>>>(partial, offsets, indptr);
    k_scan_final<<<SCAN_NB, 256, 0, stream>>>(cnt, offsets, indptr);
    k_fill<<<(NE + 255) / 256, 256, 0, stream>>>(dst, src, cnt, src_perm, NE);

    const int g64 = (NN + 63) / 64;  // 782 blocks, 4 waves each
    const int g32 = (NN + 31) / 32;  // MLP RT=2 grid
    const int gsm = (NN + 15) / 16;  // softmax: 16 nodes/block

    // GAT layer 1 (LDS-tiled GEMM, el/er fused)
    k_gemm_lds<<<g64, 256, 0, stream>>>(features, 1, W1T, featb, flag, NN, FIN, el, er, al1c,
                                        ar1c);
    k_softmax<<<gsm, 256, 0, stream>>>(el, er, src_perm, indptr, alpha_perm, inv_s, NN);
    k_agg<<<NN, HDIM, 0, stream>>>(featb, alpha_perm, src_perm, indptr, inv_s, b1c, xbf, NN);

    // GAT layer 2
    k_gemm_lds<<<g64, 256, 0, stream>>>(xbf, 0, W2T, featb, flag, NN, HDIM, el, er, al2c, ar2c);
    k_softmax<<<gsm, 256, 0, stream>>>(el, er, src_perm, indptr, alpha_perm, inv_s, NN);
    k_agg<<<NN, HDIM, 0, stream>>>(featb, alpha_perm, src_perm, indptr, inv_s, b2c, xbf, NN);

    // MLP
    k_gemm<4, 2><<<g32, 64, 0, stream>>>(xbf, Wm1T, mlph, 0, bm1c, flag, NN, HDIM, 1);
    k_gemm<4, 2><<<g32, 64, 0, stream>>>(mlph, Wm2T, d_out, 1, bm2c, flag, NN, 64, 0);
}

// Round 9
// 401.262 us; speedup vs baseline: 2.3472x; 1.0595x over previous
//
#include <hip/hip_runtime.h>
#include <hip/hip_bf16.h>

// ---- problem constants (fixed by reference) ----
#define NN 50000
#define NE 800000
#define FIN 256
#define HEADS_H 3
#define HDIM 192
#define NEG_SLOPE 0.2f
#define CHUNK 128        // edges staged in LDS per pass in k_agg_sm
#define SCAN_ELEMS 512
#define SCAN_NB ((NN + SCAN_ELEMS - 1) / SCAN_ELEMS)  // 98
#define BK 64            // layer-GEMM K-chunk
#define W1_PAD 200       // k_mlp LDS row strides (elems): +8 pad -> 2-way bank conflict only
#define W2_PAD 72
#define H_PAD 72

typedef __attribute__((ext_vector_type(8))) short frag8;
typedef __attribute__((ext_vector_type(4))) float f32x4;
typedef __attribute__((ext_vector_type(2))) unsigned u32x2;
typedef unsigned short u16;

__device__ inline u16 f2b(float x) {
    __hip_bfloat16 h = __float2bfloat16(x);
    return __builtin_bit_cast(u16, h);
}
__device__ inline float b2f(u16 b) {
    __hip_bfloat16 h = __builtin_bit_cast(__hip_bfloat16, b);
    return __bfloat162float(h);
}
__device__ inline float b2f_lo(unsigned v) { return __builtin_bit_cast(float, v << 16); }
__device__ inline float b2f_hi(unsigned v) { return __builtin_bit_cast(float, v & 0xffff0000u); }

__device__ inline int wave_sum_i(int v) {
#pragma unroll
    for (int off = 32; off > 0; off >>= 1) v += __shfl_xor(v, off, 64);
    return v;
}

// ---------------- utility ----------------
__global__ void k_fill_pattern(u16* __restrict__ p, int n, u16 v) {
    int i = blockIdx.x * blockDim.x + threadIdx.x;
    if (i < n) p[i] = v;
}
__global__ void k_zero(int* __restrict__ p, int n) {
    int i = blockIdx.x * blockDim.x + threadIdx.x;
    if (i < n) p[i] = 0;
}

__global__ void k_sniff(const unsigned* __restrict__ p, int* __restrict__ flag) {
    __shared__ int cnt_s;
    if (threadIdx.x == 0) cnt_s = 0;
    __syncthreads();
    int c = 0;
    for (int i = threadIdx.x; i < 4096; i += 256) {
        float v = __builtin_bit_cast(float, p[i]);
        float a = fabsf(v);
        if (a > 1e-4f && a < 100.f) c++;
    }
    atomicAdd(&cnt_s, c);
    __syncthreads();
    if (threadIdx.x == 0) *flag = (cnt_s > 2048) ? 1 : 0;  // 1 = inputs are fp32
}

__global__ void k_cvt8(const void* i0, const void* i1, const void* i2, const void* i3,
                       const void* i4, const void* i5, const void* i6, const void* i7,
                       u16* o0, u16* o1, u16* o2, u16* o3, u16* o4, u16* o5, u16* o6, u16* o7,
                       const int* __restrict__ flag) {
    const void* ins[8] = {i0, i1, i2, i3, i4, i5, i6, i7};
    u16* outs[8] = {o0, o1, o2, o3, o4, o5, o6, o7};
    const int ns[8] = {HDIM, HDIM, HDIM, HDIM, HDIM, HDIM, 64, 64};
    int b = blockIdx.x;
    int n = ns[b];
    const void* in = ins[b];
    u16* out = outs[b];
    int f = *flag;
    for (int i = threadIdx.x; i < n; i += 256) {
        out[i] = f ? f2b(((const float*)in)[i]) : ((const u16*)in)[i];
    }
}

__global__ void k_transpose4(const void* __restrict__ B0, const void* __restrict__ B1,
                             const void* __restrict__ B2, const void* __restrict__ B3,
                             u16* __restrict__ T0, u16* __restrict__ T1, u16* __restrict__ T2,
                             u16* __restrict__ T3, const int* __restrict__ flag) {
    const int n0 = FIN * HDIM, n1 = HDIM * HDIM, n2 = HDIM * 64, n3 = 64 * 64;
    int gi = blockIdx.x * 256 + threadIdx.x;
    const void* B;
    u16* T;
    int K, N, i;
    if (gi < n0) { B = B0; T = T0; K = FIN; N = HDIM; i = gi; }
    else if (gi < n0 + n1) { B = B1; T = T1; K = HDIM; N = HDIM; i = gi - n0; }
    else if (gi < n0 + n1 + n2) { B = B2; T = T2; K = HDIM; N = 64; i = gi - n0 - n1; }
    else if (gi < n0 + n1 + n2 + n3) { B = B3; T = T3; K = 64; N = 64; i = gi - n0 - n1 - n2; }
    else return;
    int k = i / N, n = i - k * N;
    u16 v = (*flag) ? f2b(((const float*)B)[i]) : ((const u16*)B)[i];
    T[n * K + k] = v;
}

// ---------------- CSR build ----------------
__global__ void k_count(const int* __restrict__ dst, int* __restrict__ cnt, int E) {
    int e = blockIdx.x * blockDim.x + threadIdx.x;
    if (e < E) atomicAdd(&cnt[dst[e]], 1);
}

__global__ void k_scan_partial(const int* __restrict__ cnt, int* __restrict__ partial) {
    int b = blockIdx.x, t = threadIdx.x;
    int i0 = b * SCAN_ELEMS + t * 2;
    int v = 0;
    if (i0 < NN) v += cnt[i0];
    if (i0 + 1 < NN) v += cnt[i0 + 1];
    v = wave_sum_i(v);
    __shared__ int wsum[4];
    if ((t & 63) == 0) wsum[t >> 6] = v;
    __syncthreads();
    if (t == 0) partial[b] = wsum[0] + wsum[1] + wsum[2] + wsum[3];
}

__global__ void k_scan_mid(const int* __restrict__ partial, int* __restrict__ offsets,
                           int* __restrict__ indptr) {
    __shared__ int s[SCAN_NB];
    int t = threadIdx.x;  // 128 >= SCAN_NB
    if (t < SCAN_NB) s[t] = partial[t];
    __syncthreads();
    for (int off = 1; off < SCAN_NB; off <<= 1) {
        int v = (t >= off && t < SCAN_NB) ? s[t - off] : 0;
        __syncthreads();
        if (t < SCAN_NB) s[t] += v;
        __syncthreads();
    }
    if (t < SCAN_NB) offsets[t] = (t == 0) ? 0 : s[t - 1];
    if (t == 0) indptr[NN] = s[SCAN_NB - 1];
}

__global__ void k_scan_final(int* __restrict__ cnt, const int* __restrict__ offsets,
                             int* __restrict__ indptr) {
    __shared__ int tsum[256];
    int b = blockIdx.x, t = threadIdx.x;
    int i0 = b * SCAN_ELEMS + t * 2;
    int c0 = (i0 < NN) ? cnt[i0] : 0;
    int c1 = (i0 + 1 < NN) ? cnt[i0 + 1] : 0;
    tsum[t] = c0 + c1;
    __syncthreads();
    for (int off = 1; off < 256; off <<= 1) {
        int v = (t >= off) ? tsum[t - off] : 0;
        __syncthreads();
        tsum[t] += v;
        __syncthreads();
    }
    int excl = offsets[b] + ((t == 0) ? 0 : tsum[t - 1]);
    if (i0 < NN) { indptr[i0] = excl; cnt[i0] = excl; }
    if (i0 + 1 < NN) { indptr[i0 + 1] = excl + c0; cnt[i0 + 1] = excl + c0; }
}

__global__ void k_fill(const int* __restrict__ dst, const int* __restrict__ srcv,
                       int* __restrict__ cursor, int* __restrict__ src_perm, int E) {
    int e = blockIdx.x * blockDim.x + threadIdx.x;
    if (e < E) {
        int p = atomicAdd(&cursor[dst[e]], 1);
        src_perm[p] = srcv[e];
    }
}

// ---------------- LDS-tiled MFMA GEMM (layer GEMMs, N=192) + el/er epilogue ----------------
__global__ __launch_bounds__(256) void k_gemm_lds(
    const void* __restrict__ A, int a_dual, const u16* __restrict__ BT,
    void* __restrict__ C, const int* __restrict__ flag, int M, int K,
    float* __restrict__ elp, float* __restrict__ erp,
    const u16* __restrict__ al, const u16* __restrict__ ar) {
    __shared__ u16 sB[2][12 * 64 * 8 * 2];  // 2 x 24 KB
    const int tid = threadIdx.x;
    const int lane = tid & 63;
    const int w = tid >> 6;
    const int c16 = lane & 15;
    const int quad = lane >> 4;
    const int m_base = blockIdx.x * 64 + w * 16;
    const int f = *flag;
    const bool a32 = a_dual && f;

    int m0 = m_base + c16;
    int arow = (m0 < M) ? m0 : (M - 1);

    f32x4 acc[12];
#pragma unroll
    for (int t = 0; t < 12; ++t) acc[t] = (f32x4)0.f;

    frag8 v[6];
    auto stageLoad = [&](int c) {
        int k0 = c * BK;
#pragma unroll
        for (int s = 0; s < 6; ++s) {
            int g = tid + s * 256;
            int n = g >> 3, k8 = g & 7;
            v[s] = *(const frag8*)(BT + (size_t)n * K + k0 + k8 * 8);
        }
    };
    auto stageWrite = [&](int buf) {
#pragma unroll
        for (int s = 0; s < 6; ++s) {
            int g = tid + s * 256;
            int n = g >> 3, k8 = g & 7;
            int t = n >> 4, cc = n & 15, kk = k8 >> 2, qq = k8 & 3;
            int gl = (kk * 12 + t) * 64 + qq * 16 + cc;
            *(frag8*)&sB[buf][gl * 8] = v[s];
        }
    };
    auto loadAc = [&](int k0, frag8* a) {
#pragma unroll
        for (int kk = 0; kk < 2; ++kk) {
            if (a32) {
                const float* ap = (const float*)A + (size_t)arow * K + k0 + kk * 32 + quad * 8;
                f32x4 f0 = *(const f32x4*)ap;
                f32x4 f1 = *(const f32x4*)(ap + 4);
                a[kk][0] = (short)f2b(f0[0]); a[kk][1] = (short)f2b(f0[1]);
                a[kk][2] = (short)f2b(f0[2]); a[kk][3] = (short)f2b(f0[3]);
                a[kk][4] = (short)f2b(f1[0]); a[kk][5] = (short)f2b(f1[1]);
                a[kk][6] = (short)f2b(f1[2]); a[kk][7] = (short)f2b(f1[3]);
            } else {
                a[kk] = *(const frag8*)((const u16*)A + (size_t)arow * K + k0 + kk * 32 + quad * 8);
            }
        }
    };

    const int nc = K / BK;
    stageLoad(0);
    stageWrite(0);
    __syncthreads();
    for (int c = 0; c < nc; ++c) {
        if (c + 1 < nc) stageLoad(c + 1);
        frag8 a[2];
        loadAc(c * BK, a);
        const int buf = c & 1;
#pragma unroll
        for (int kk = 0; kk < 2; ++kk) {
#pragma unroll
            for (int t = 0; t < 12; ++t) {
                frag8 b = *(const frag8*)&sB[buf][((kk * 12 + t) * 64 + lane) * 8];
                acc[t] = __builtin_amdgcn_mfma_f32_16x16x32_bf16(a[kk], b, acc[t], 0, 0, 0);
            }
        }
        if (c + 1 < nc) stageWrite((c + 1) & 1);
        __syncthreads();
    }

#pragma unroll
    for (int t = 0; t < 12; ++t) {
        int col = t * 16 + c16;
#pragma unroll
        for (int rr = 0; rr < 4; ++rr) {
            int m = m_base + quad * 4 + rr;
            if (m < M)
                ((__hip_bfloat16*)C)[(size_t)m * HDIM + col] = __float2bfloat16(acc[t][rr]);
        }
    }

    float alv[12], arv[12];
#pragma unroll
    for (int t = 0; t < 12; ++t) {
        alv[t] = b2f(al[t * 16 + c16]);
        arv[t] = b2f(ar[t * 16 + c16]);
    }
#pragma unroll
    for (int rr = 0; rr < 4; ++rr) {
        int m = m_base + quad * 4 + rr;
        float pl[HEADS_H] = {0.f, 0.f, 0.f};
        float pr[HEADS_H] = {0.f, 0.f, 0.f};
#pragma unroll
        for (int t = 0; t < 12; ++t) {
            int h = t >> 2;
            pl[h] += acc[t][rr] * alv[t];
            pr[h] += acc[t][rr] * arv[t];
        }
#pragma unroll
        for (int h = 0; h < HEADS_H; ++h) {
#pragma unroll
            for (int off = 1; off < 16; off <<= 1) {
                pl[h] += __shfl_xor(pl[h], off, 64);
                pr[h] += __shfl_xor(pr[h], off, 64);
            }
            if (c16 == 0 && m < M) {
                elp[m * HEADS_H + h] = pl[h];
                erp[m * HEADS_H + h] = pr[h];
            }
        }
    }
}

// ---------------- fused MLP: out = (relu(x@Wm1+bm1))@Wm2+bm2 ----------------
// 256 threads = 4 waves x 16 rows. Both weights + h staged in padded LDS.
__global__ __launch_bounds__(256) void k_mlp(const u16* __restrict__ xbf,
                                             const u16* __restrict__ Wm1T,
                                             const u16* __restrict__ Wm2T,
                                             const u16* __restrict__ bm1,
                                             const u16* __restrict__ bm2, void* __restrict__ out,
                                             const int* __restrict__ flag, int M) {
    __shared__ u16 sW1[64 * W1_PAD];  // [n][K=192] padded
    __shared__ u16 sW2[64 * W2_PAD];  // [n][K=64] padded
    __shared__ u16 sH[64 * H_PAD];    // h rows padded
    const int tid = threadIdx.x;
    const int lane = tid & 63, w = tid >> 6;
    const int c16 = lane & 15, quad = lane >> 4;
    const int m_base = blockIdx.x * 64 + w * 16;
    const bool c32 = *flag != 0;

    // stage weights
#pragma unroll
    for (int s = 0; s < 6; ++s) {
        int g = tid + s * 256;            // 1536 groups: n = g/24, k8 = g%24
        int n = g / 24, k8 = g - n * 24;
        *(frag8*)&sW1[n * W1_PAD + k8 * 8] = *(const frag8*)(Wm1T + n * 192 + k8 * 8);
    }
#pragma unroll
    for (int s = 0; s < 2; ++s) {
        int g = tid + s * 256;            // 512 groups: n = g/8, k8 = g%8
        int n = g >> 3, k8 = g & 7;
        *(frag8*)&sW2[n * W2_PAD + k8 * 8] = *(const frag8*)(Wm2T + n * 64 + k8 * 8);
    }
    int m0 = m_base + c16;
    int arow = (m0 < M) ? m0 : (M - 1);
    __syncthreads();

    // GEMM1: h = relu(x @ Wm1 + bm1), 16x64 per wave
    f32x4 acc1[4];
#pragma unroll
    for (int t = 0; t < 4; ++t) acc1[t] = (f32x4)0.f;
    for (int k0 = 0; k0 < 192; k0 += 32) {
        frag8 a = *(const frag8*)(xbf + (size_t)arow * HDIM + k0 + quad * 8);
#pragma unroll
        for (int t = 0; t < 4; ++t) {
            frag8 b = *(const frag8*)&sW1[(t * 16 + c16) * W1_PAD + k0 + quad * 8];
            acc1[t] = __builtin_amdgcn_mfma_f32_16x16x32_bf16(a, b, acc1[t], 0, 0, 0);
        }
    }
#pragma unroll
    for (int t = 0; t < 4; ++t) {
        float bv = b2f(bm1[t * 16 + c16]);
#pragma unroll
        for (int rr = 0; rr < 4; ++rr) {
            float v = fmaxf(acc1[t][rr] + bv, 0.f);
            sH[(w * 16 + quad * 4 + rr) * H_PAD + t * 16 + c16] = f2b(v);
        }
    }
    __syncthreads();

    // GEMM2: out = h @ Wm2 + bm2
    f32x4 acc2[4];
#pragma unroll
    for (int t = 0; t < 4; ++t) acc2[t] = (f32x4)0.f;
#pragma unroll
    for (int k0 = 0; k0 < 64; k0 += 32) {
        frag8 a = *(const frag8*)&sH[(w * 16 + c16) * H_PAD + k0 + quad * 8];
#pragma unroll
        for (int t = 0; t < 4; ++t) {
            frag8 b = *(const frag8*)&sW2[(t * 16 + c16) * W2_PAD + k0 + quad * 8];
            acc2[t] = __builtin_amdgcn_mfma_f32_16x16x32_bf16(a, b, acc2[t], 0, 0, 0);
        }
    }
#pragma unroll
    for (int t = 0; t < 4; ++t) {
        int col = t * 16 + c16;
        float bv = b2f(bm2[col]);
#pragma unroll
        for (int rr = 0; rr < 4; ++rr) {
            int m = m_base + quad * 4 + rr;
            if (m < M) {
                float v = acc2[t][rr] + bv;
                if (c32) ((float*)out)[(size_t)m * 64 + col] = v;
                else ((__hip_bfloat16*)out)[(size_t)m * 64 + col] = __float2bfloat16(v);
            }
        }
    }
}

// ---------------- fused softmax + aggregation (one node per 192-thread block) -------
// wave w (of 3) owns head w for the softmax phase; gather uses 4 slots x 48 threads
// with 4 always-independent feat loads per group (OOB clamped to dup addr, weight 0).
__global__ void k_agg_sm(const u16* __restrict__ feat, const float* __restrict__ el,
                         const float* __restrict__ er, const int* __restrict__ src_perm,
                         const int* __restrict__ indptr, const u16* __restrict__ bias,
                         u16* __restrict__ outb, int n_nodes) {
    __shared__ int ssrc[CHUNK];
    __shared__ float salpha[CHUNK * HEADS_H];
    __shared__ float sinv[4];
    __shared__ float smax[4];
    __shared__ f32x4 spart[3 * 48];
    int n = blockIdx.x;
    int t = threadIdx.x;           // 0..191
    int wave = t >> 6, lane = t & 63;
    int slot = t / 48, u = t - slot * 48, h = u >> 4;
    int beg = indptr[n], end = indptr[n + 1];
    int lenT = end - beg;
    const u16* fbase = feat + 4 * u;
    float a0 = 0.f, a1 = 0.f, a2 = 0.f, a3 = 0.f;

    auto gatherChunk = [&](int len) {
        for (int j0 = slot; j0 < len; j0 += 16) {
            int jb = j0 + 4, jc = j0 + 8, jd = j0 + 12;
            bool vb = jb < len, vc = jc < len, vd = jd < len;
            int sa = ssrc[j0];
            int sb = ssrc[vb ? jb : j0];
            int sc = ssrc[vc ? jc : j0];
            int sd = ssrc[vd ? jd : j0];
            float wa = salpha[j0 * HEADS_H + h];
            float wb = vb ? salpha[jb * HEADS_H + h] : 0.f;
            float wc = vc ? salpha[jc * HEADS_H + h] : 0.f;
            float wd = vd ? salpha[jd * HEADS_H + h] : 0.f;
            u32x2 va = *(const u32x2*)(fbase + (size_t)sa * HDIM);
            u32x2 vbv = *(const u32x2*)(fbase + (size_t)sb * HDIM);
            u32x2 vcv = *(const u32x2*)(fbase + (size_t)sc * HDIM);
            u32x2 vdv = *(const u32x2*)(fbase + (size_t)sd * HDIM);
            a0 += wa * b2f_lo(va.x); a1 += wa * b2f_hi(va.x);
            a2 += wa * b2f_lo(va.y); a3 += wa * b2f_hi(va.y);
            a0 += wb * b2f_lo(vbv.x); a1 += wb * b2f_hi(vbv.x);
            a2 += wb * b2f_lo(vbv.y); a3 += wb * b2f_hi(vbv.y);
            a0 += wc * b2f_lo(vcv.x); a1 += wc * b2f_hi(vcv.x);
            a2 += wc * b2f_lo(vcv.y); a3 += wc * b2f_hi(vcv.y);
            a0 += wd * b2f_lo(vdv.x); a1 += wd * b2f_hi(vdv.x);
            a2 += wd * b2f_lo(vdv.y); a3 += wd * b2f_hi(vdv.y);
        }
    };

    float erh = er[n * HEADS_H + wave];

    if (lenT <= CHUNK) {
        for (int j = t; j < lenT; j += 192) ssrc[j] = src_perm[beg + j];
        __syncthreads();
        float m = -INFINITY;
        for (int j = lane; j < lenT; j += 64) {
            int s = ssrc[j];
            float ev = el[s * HEADS_H + wave] + erh;
            ev = (ev > 0.f) ? ev : NEG_SLOPE * ev;
            salpha[j * HEADS_H + wave] = ev;
            m = fmaxf(m, ev);
        }
#pragma unroll
        for (int off = 32; off > 0; off >>= 1) m = fmaxf(m, __shfl_xor(m, off, 64));
        float s = 0.f;
        for (int j = lane; j < lenT; j += 64) {
            float ex = __expf(salpha[j * HEADS_H + wave] - m);
            salpha[j * HEADS_H + wave] = ex;
            s += ex;
        }
#pragma unroll
        for (int off = 32; off > 0; off >>= 1) s += __shfl_xor(s, off, 64);
        if (lane == 0) sinv[wave] = (s > 0.f) ? 1.f / s : 0.f;
        __syncthreads();
        gatherChunk(lenT);
    } else {
        // pass 1: global two-pass stats per head
        float m = -INFINITY;
        for (int j = lane; j < lenT; j += 64) {
            int s = src_perm[beg + j];
            float ev = el[s * HEADS_H + wave] + erh;
            ev = (ev > 0.f) ? ev : NEG_SLOPE * ev;
            m = fmaxf(m, ev);
        }
#pragma unroll
        for (int off = 32; off > 0; off >>= 1) m = fmaxf(m, __shfl_xor(m, off, 64));
        float s = 0.f;
        for (int j = lane; j < lenT; j += 64) {
            int sp = src_perm[beg + j];
            float ev = el[sp * HEADS_H + wave] + erh;
            ev = (ev > 0.f) ? ev : NEG_SLOPE * ev;
            s += __expf(ev - m);
        }
#pragma unroll
        for (int off = 32; off > 0; off >>= 1) s += __shfl_xor(s, off, 64);
        if (lane == 0) {
            sinv[wave] = (s > 0.f) ? 1.f / s : 0.f;
            smax[wave] = m;
        }
        __syncthreads();
        float mm = smax[wave];
        for (int c0 = 0; c0 < lenT; c0 += CHUNK) {
            int len = min(CHUNK, lenT - c0);
            __syncthreads();
            for (int j = t; j < len; j += 192) ssrc[j] = src_perm[beg + c0 + j];
            __syncthreads();
            for (int j = lane; j < len; j += 64) {
                int sp = ssrc[j];
                float ev = el[sp * HEADS_H + wave] + erh;
                ev = (ev > 0.f) ? ev : NEG_SLOPE * ev;
                salpha[j * HEADS_H + wave] = __expf(ev - mm);
            }
            __syncthreads();
            gatherChunk(len);
        }
    }

    __syncthreads();
    if (slot > 0) {
        f32x4 p; p[0] = a0; p[1] = a1; p[2] = a2; p[3] = a3;
        spart[(slot - 1) * 48 + u] = p;
    }
    __syncthreads();
    if (slot == 0) {
        f32x4 p0 = spart[u], p1 = spart[48 + u], p2 = spart[96 + u];
        float is = sinv[h];
        u32x2 bv = *(const u32x2*)(bias + 4 * u);
        float v0 = (a0 + p0[0] + p1[0] + p2[0]) * is + b2f_lo(bv.x);
        float v1 = (a1 + p0[1] + p1[1] + p2[1]) * is + b2f_hi(bv.x);
        float v2 = (a2 + p0[2] + p1[2] + p2[2]) * is + b2f_lo(bv.y);
        float v3 = (a3 + p0[3] + p1[3] + p2[3]) * is + b2f_hi(bv.y);
        v0 = fmaxf(v0, 0.f); v1 = fmaxf(v1, 0.f);
        v2 = fmaxf(v2, 0.f); v3 = fmaxf(v3, 0.f);
        u32x2 o;
        o.x = (unsigned)f2b(v0) | ((unsigned)f2b(v1) << 16);
        o.y = (unsigned)f2b(v2) | ((unsigned)f2b(v3) << 16);
        *(u32x2*)(outb + (size_t)n * HDIM + 4 * u) = o;
    }
}

// ---------------- launch ----------------
extern "C" void kernel_launch(void* const* d_in, const int* in_sizes, int n_in,
                              void* d_out, int out_size, void* d_ws, size_t ws_size,
                              hipStream_t stream) {
    const void* features = d_in[0];
    const int* src = (const int*)d_in[1];
    const int* dst = (const int*)d_in[2];
    const void* W1 = d_in[3];
    const void* al1 = d_in[4];
    const void* ar1 = d_in[5];
    const void* b1 = d_in[6];
    const void* W2 = d_in[7];
    const void* al2 = d_in[8];
    const void* ar2 = d_in[9];
    const void* b2 = d_in[10];
    const void* Wm1 = d_in[11];
    const void* bm1 = d_in[12];
    const void* Wm2 = d_in[13];
    const void* bm2 = d_in[14];

    char* ws = (char*)d_ws;
    size_t off = 0;
    auto alloc = [&](size_t bytes) -> void* {
        void* p = ws + off;
        off = (off + bytes + 255) & ~(size_t)255;
        return p;
    };
    int* flag = (int*)alloc(4);
    u16* featb = (u16*)alloc((size_t)NN * HDIM * 2);
    u16* xbf = (u16*)alloc((size_t)NN * HDIM * 2);
    float* el = (float*)alloc((size_t)NN * HEADS_H * 4);
    float* er = (float*)alloc((size_t)NN * HEADS_H * 4);
    int* indptr = (int*)alloc((size_t)(NN + 1) * 4);
    int* cnt = (int*)alloc((size_t)NN * 4);
    int* src_perm = (int*)alloc((size_t)NE * 4);
    int* partial = (int*)alloc((size_t)SCAN_NB * 4);
    int* offsets = (int*)alloc((size_t)SCAN_NB * 4);
    u16* W1T = (u16*)alloc((size_t)FIN * HDIM * 2);
    u16* W2T = (u16*)alloc((size_t)HDIM * HDIM * 2);
    u16* Wm1T = (u16*)alloc((size_t)HDIM * 64 * 2);
    u16* Wm2T = (u16*)alloc((size_t)64 * 64 * 2);
    u16* al1c = (u16*)alloc(HDIM * 2);
    u16* ar1c = (u16*)alloc(HDIM * 2);
    u16* b1c = (u16*)alloc(HDIM * 2);
    u16* al2c = (u16*)alloc(HDIM * 2);
    u16* ar2c = (u16*)alloc(HDIM * 2);
    u16* b2c = (u16*)alloc(HDIM * 2);
    u16* bm1c = (u16*)alloc(64 * 2);
    u16* bm2c = (u16*)alloc(64 * 2);

    if (ws_size < off) {
        k_fill_pattern<<<(out_size + 255) / 256, 256, 0, stream>>>((u16*)d_out, out_size, 0x3F80);
        return;
    }

    k_sniff<<<1, 256, 0, stream>>>((const unsigned*)features, flag);

    k_cvt8<<<8, 256, 0, stream>>>(al1, ar1, b1, al2, ar2, b2, bm1, bm2, al1c, ar1c, b1c, al2c,
                                  ar2c, b2c, bm1c, bm2c, flag);
    {
        const int tot = FIN * HDIM + HDIM * HDIM + HDIM * 64 + 64 * 64;
        k_transpose4<<<(tot + 255) / 256, 256, 0, stream>>>(W1, W2, Wm1, Wm2, W1T, W2T, Wm1T,
                                                            Wm2T, flag);
    }

    // CSR by dst
    k_zero<<<(NN + 255) / 256, 256, 0, stream>>>(cnt, NN);
    k_count<<<(NE + 255) / 256, 256, 0, stream>>>(dst, cnt, NE);
    k_scan_partial<<<SCAN_NB, 256, 0, stream>>>(cnt, partial);
    k_scan_mid<<<1, 128, 0, stream>>>(partial, offsets, indptr);
    k_scan_final<<<SCAN_NB, 256, 0, stream>>>(cnt, offsets, indptr);
    k_fill<<<(NE + 255) / 256, 256, 0, stream>>>(dst, src, cnt, src_perm, NE);

    const int g64 = (NN + 63) / 64;  // 782 blocks

    // GAT layer 1
    k_gemm_lds<<<g64, 256, 0, stream>>>(features, 1, W1T, featb, flag, NN, FIN, el, er, al1c,
                                        ar1c);
    k_agg_sm<<<NN, 192, 0, stream>>>(featb, el, er, src_perm, indptr, b1c, xbf, NN);

    // GAT layer 2
    k_gemm_lds<<<g64, 256, 0, stream>>>(xbf, 0, W2T, featb, flag, NN, HDIM, el, er, al2c, ar2c);
    k_agg_sm<<<NN, 192, 0, stream>>>(featb, el, er, src_perm, indptr, b2c, xbf, NN);

    // fused MLP
    k_mlp<<<g64, 256, 0, stream>>>(xbf, Wm1T, Wm2T, bm1c, bm2c, d_out, flag, NN);
}

// Round 10
// 373.070 us; speedup vs baseline: 2.5246x; 1.0756x over previous
//
#include <hip/hip_runtime.h>
#include <hip/hip_bf16.h>

// ---- problem constants (fixed by reference) ----
#define NN 50000
#define NE 800000
#define FIN 256
#define HEADS_H 3
#define HDIM 192
#define NEG_SLOPE 0.2f
#define CHUNK 128        // edges per online-softmax chunk in k_agg_sm
#define SCAN_ELEMS 512
#define SCAN_NB ((NN + SCAN_ELEMS - 1) / SCAN_ELEMS)  // 98
#define BK 64            // layer-GEMM K-chunk
#define W1_PAD 200
#define W2_PAD 72
#define H_PAD 72

typedef __attribute__((ext_vector_type(8))) short frag8;
typedef __attribute__((ext_vector_type(4))) float f32x4;
typedef __attribute__((ext_vector_type(2))) unsigned u32x2;
typedef unsigned short u16;

__device__ inline u16 f2b(float x) {
    __hip_bfloat16 h = __float2bfloat16(x);
    return __builtin_bit_cast(u16, h);
}
__device__ inline float b2f(u16 b) {
    __hip_bfloat16 h = __builtin_bit_cast(__hip_bfloat16, b);
    return __bfloat162float(h);
}
__device__ inline float b2f_lo(unsigned v) { return __builtin_bit_cast(float, v << 16); }
__device__ inline float b2f_hi(unsigned v) { return __builtin_bit_cast(float, v & 0xffff0000u); }

__device__ inline int wave_sum_i(int v) {
#pragma unroll
    for (int off = 32; off > 0; off >>= 1) v += __shfl_xor(v, off, 64);
    return v;
}

// ---------------- utility ----------------
__global__ void k_fill_pattern(u16* __restrict__ p, int n, u16 v) {
    int i = blockIdx.x * blockDim.x + threadIdx.x;
    if (i < n) p[i] = v;
}
__global__ void k_zero(int* __restrict__ p, int n) {
    int i = blockIdx.x * blockDim.x + threadIdx.x;
    if (i < n) p[i] = 0;
}

__global__ void k_sniff(const unsigned* __restrict__ p, int* __restrict__ flag) {
    __shared__ int cnt_s;
    if (threadIdx.x == 0) cnt_s = 0;
    __syncthreads();
    int c = 0;
    for (int i = threadIdx.x; i < 4096; i += 256) {
        float v = __builtin_bit_cast(float, p[i]);
        float a = fabsf(v);
        if (a > 1e-4f && a < 100.f) c++;
    }
    atomicAdd(&cnt_s, c);
    __syncthreads();
    if (threadIdx.x == 0) *flag = (cnt_s > 2048) ? 1 : 0;  // 1 = inputs are fp32
}

__global__ void k_cvt8(const void* i0, const void* i1, const void* i2, const void* i3,
                       const void* i4, const void* i5, const void* i6, const void* i7,
                       u16* o0, u16* o1, u16* o2, u16* o3, u16* o4, u16* o5, u16* o6, u16* o7,
                       const int* __restrict__ flag) {
    const void* ins[8] = {i0, i1, i2, i3, i4, i5, i6, i7};
    u16* outs[8] = {o0, o1, o2, o3, o4, o5, o6, o7};
    const int ns[8] = {HDIM, HDIM, HDIM, HDIM, HDIM, HDIM, 64, 64};
    int b = blockIdx.x;
    int n = ns[b];
    const void* in = ins[b];
    u16* out = outs[b];
    int f = *flag;
    for (int i = threadIdx.x; i < n; i += 256) {
        out[i] = f ? f2b(((const float*)in)[i]) : ((const u16*)in)[i];
    }
}

__global__ void k_transpose4(const void* __restrict__ B0, const void* __restrict__ B1,
                             const void* __restrict__ B2, const void* __restrict__ B3,
                             u16* __restrict__ T0, u16* __restrict__ T1, u16* __restrict__ T2,
                             u16* __restrict__ T3, const int* __restrict__ flag) {
    const int n0 = FIN * HDIM, n1 = HDIM * HDIM, n2 = HDIM * 64, n3 = 64 * 64;
    int gi = blockIdx.x * 256 + threadIdx.x;
    const void* B;
    u16* T;
    int K, N, i;
    if (gi < n0) { B = B0; T = T0; K = FIN; N = HDIM; i = gi; }
    else if (gi < n0 + n1) { B = B1; T = T1; K = HDIM; N = HDIM; i = gi - n0; }
    else if (gi < n0 + n1 + n2) { B = B2; T = T2; K = HDIM; N = 64; i = gi - n0 - n1; }
    else if (gi < n0 + n1 + n2 + n3) { B = B3; T = T3; K = 64; N = 64; i = gi - n0 - n1 - n2; }
    else return;
    int k = i / N, n = i - k * N;
    u16 v = (*flag) ? f2b(((const float*)B)[i]) : ((const u16*)B)[i];
    T[n * K + k] = v;
}

// ---------------- CSR build ----------------
__global__ void k_count(const int* __restrict__ dst, int* __restrict__ cnt, int E) {
    int e = blockIdx.x * blockDim.x + threadIdx.x;
    if (e < E) atomicAdd(&cnt[dst[e]], 1);
}

__global__ void k_scan_partial(const int* __restrict__ cnt, int* __restrict__ partial) {
    int b = blockIdx.x, t = threadIdx.x;
    int i0 = b * SCAN_ELEMS + t * 2;
    int v = 0;
    if (i0 < NN) v += cnt[i0];
    if (i0 + 1 < NN) v += cnt[i0 + 1];
    v = wave_sum_i(v);
    __shared__ int wsum[4];
    if ((t & 63) == 0) wsum[t >> 6] = v;
    __syncthreads();
    if (t == 0) partial[b] = wsum[0] + wsum[1] + wsum[2] + wsum[3];
}

__global__ void k_scan_mid(const int* __restrict__ partial, int* __restrict__ offsets,
                           int* __restrict__ indptr) {
    __shared__ int s[SCAN_NB];
    int t = threadIdx.x;  // 128 >= SCAN_NB
    if (t < SCAN_NB) s[t] = partial[t];
    __syncthreads();
    for (int off = 1; off < SCAN_NB; off <<= 1) {
        int v = (t >= off && t < SCAN_NB) ? s[t - off] : 0;
        __syncthreads();
        if (t < SCAN_NB) s[t] += v;
        __syncthreads();
    }
    if (t < SCAN_NB) offsets[t] = (t == 0) ? 0 : s[t - 1];
    if (t == 0) indptr[NN] = s[SCAN_NB - 1];
}

__global__ void k_scan_final(int* __restrict__ cnt, const int* __restrict__ offsets,
                             int* __restrict__ indptr) {
    __shared__ int tsum[256];
    int b = blockIdx.x, t = threadIdx.x;
    int i0 = b * SCAN_ELEMS + t * 2;
    int c0 = (i0 < NN) ? cnt[i0] : 0;
    int c1 = (i0 + 1 < NN) ? cnt[i0 + 1] : 0;
    tsum[t] = c0 + c1;
    __syncthreads();
    for (int off = 1; off < 256; off <<= 1) {
        int v = (t >= off) ? tsum[t - off] : 0;
        __syncthreads();
        tsum[t] += v;
        __syncthreads();
    }
    int excl = offsets[b] + ((t == 0) ? 0 : tsum[t - 1]);
    if (i0 < NN) { indptr[i0] = excl; cnt[i0] = excl; }
    if (i0 + 1 < NN) { indptr[i0 + 1] = excl + c0; cnt[i0 + 1] = excl + c0; }
}

__global__ void k_fill(const int* __restrict__ dst, const int* __restrict__ srcv,
                       int* __restrict__ cursor, int* __restrict__ src_perm, int E) {
    int e = blockIdx.x * blockDim.x + threadIdx.x;
    if (e < E) {
        int p = atomicAdd(&cursor[dst[e]], 1);
        src_perm[p] = srcv[e];
    }
}

// ---------------- LDS-tiled MFMA GEMM (layer GEMMs, N=192) + el/er epilogue ----------------
__global__ __launch_bounds__(256) void k_gemm_lds(
    const void* __restrict__ A, int a_dual, const u16* __restrict__ BT,
    void* __restrict__ C, const int* __restrict__ flag, int M, int K,
    float* __restrict__ elp, float* __restrict__ erp,
    const u16* __restrict__ al, const u16* __restrict__ ar) {
    __shared__ u16 sB[2][12 * 64 * 8 * 2];  // 2 x 24 KB
    const int tid = threadIdx.x;
    const int lane = tid & 63;
    const int w = tid >> 6;
    const int c16 = lane & 15;
    const int quad = lane >> 4;
    const int m_base = blockIdx.x * 64 + w * 16;
    const int f = *flag;
    const bool a32 = a_dual && f;

    int m0 = m_base + c16;
    int arow = (m0 < M) ? m0 : (M - 1);

    f32x4 acc[12];
#pragma unroll
    for (int t = 0; t < 12; ++t) acc[t] = (f32x4)0.f;

    frag8 v[6];
    auto stageLoad = [&](int c) {
        int k0 = c * BK;
#pragma unroll
        for (int s = 0; s < 6; ++s) {
            int g = tid + s * 256;
            int n = g >> 3, k8 = g & 7;
            v[s] = *(const frag8*)(BT + (size_t)n * K + k0 + k8 * 8);
        }
    };
    auto stageWrite = [&](int buf) {
#pragma unroll
        for (int s = 0; s < 6; ++s) {
            int g = tid + s * 256;
            int n = g >> 3, k8 = g & 7;
            int t = n >> 4, cc = n & 15, kk = k8 >> 2, qq = k8 & 3;
            int gl = (kk * 12 + t) * 64 + qq * 16 + cc;
            *(frag8*)&sB[buf][gl * 8] = v[s];
        }
    };
    auto loadAc = [&](int k0, frag8* a) {
#pragma unroll
        for (int kk = 0; kk < 2; ++kk) {
            if (a32) {
                const float* ap = (const float*)A + (size_t)arow * K + k0 + kk * 32 + quad * 8;
                f32x4 f0 = *(const f32x4*)ap;
                f32x4 f1 = *(const f32x4*)(ap + 4);
                a[kk][0] = (short)f2b(f0[0]); a[kk][1] = (short)f2b(f0[1]);
                a[kk][2] = (short)f2b(f0[2]); a[kk][3] = (short)f2b(f0[3]);
                a[kk][4] = (short)f2b(f1[0]); a[kk][5] = (short)f2b(f1[1]);
                a[kk][6] = (short)f2b(f1[2]); a[kk][7] = (short)f2b(f1[3]);
            } else {
                a[kk] = *(const frag8*)((const u16*)A + (size_t)arow * K + k0 + kk * 32 + quad * 8);
            }
        }
    };

    const int nc = K / BK;
    stageLoad(0);
    stageWrite(0);
    __syncthreads();
    for (int c = 0; c < nc; ++c) {
        if (c + 1 < nc) stageLoad(c + 1);
        frag8 a[2];
        loadAc(c * BK, a);
        const int buf = c & 1;
#pragma unroll
        for (int kk = 0; kk < 2; ++kk) {
#pragma unroll
            for (int t = 0; t < 12; ++t) {
                frag8 b = *(const frag8*)&sB[buf][((kk * 12 + t) * 64 + lane) * 8];
                acc[t] = __builtin_amdgcn_mfma_f32_16x16x32_bf16(a[kk], b, acc[t], 0, 0, 0);
            }
        }
        if (c + 1 < nc) stageWrite((c + 1) & 1);
        __syncthreads();
    }

#pragma unroll
    for (int t = 0; t < 12; ++t) {
        int col = t * 16 + c16;
#pragma unroll
        for (int rr = 0; rr < 4; ++rr) {
            int m = m_base + quad * 4 + rr;
            if (m < M)
                ((__hip_bfloat16*)C)[(size_t)m * HDIM + col] = __float2bfloat16(acc[t][rr]);
        }
    }

    float alv[12], arv[12];
#pragma unroll
    for (int t = 0; t < 12; ++t) {
        alv[t] = b2f(al[t * 16 + c16]);
        arv[t] = b2f(ar[t * 16 + c16]);
    }
#pragma unroll
    for (int rr = 0; rr < 4; ++rr) {
        int m = m_base + quad * 4 + rr;
        float pl[HEADS_H] = {0.f, 0.f, 0.f};
        float pr[HEADS_H] = {0.f, 0.f, 0.f};
#pragma unroll
        for (int t = 0; t < 12; ++t) {
            int h = t >> 2;
            pl[h] += acc[t][rr] * alv[t];
            pr[h] += acc[t][rr] * arv[t];
        }
#pragma unroll
        for (int h = 0; h < HEADS_H; ++h) {
#pragma unroll
            for (int off = 1; off < 16; off <<= 1) {
                pl[h] += __shfl_xor(pl[h], off, 64);
                pr[h] += __shfl_xor(pr[h], off, 64);
            }
            if (c16 == 0 && m < M) {
                elp[m * HEADS_H + h] = pl[h];
                erp[m * HEADS_H + h] = pr[h];
            }
        }
    }
}

// ---------------- fused MLP: out = (relu(x@Wm1+bm1))@Wm2+bm2 ----------------
__global__ __launch_bounds__(256) void k_mlp(const u16* __restrict__ xbf,
                                             const u16* __restrict__ Wm1T,
                                             const u16* __restrict__ Wm2T,
                                             const u16* __restrict__ bm1,
                                             const u16* __restrict__ bm2, void* __restrict__ out,
                                             const int* __restrict__ flag, int M) {
    __shared__ u16 sW1[64 * W1_PAD];
    __shared__ u16 sW2[64 * W2_PAD];
    __shared__ u16 sH[64 * H_PAD];
    const int tid = threadIdx.x;
    const int lane = tid & 63, w = tid >> 6;
    const int c16 = lane & 15, quad = lane >> 4;
    const int m_base = blockIdx.x * 64 + w * 16;
    const bool c32 = *flag != 0;

#pragma unroll
    for (int s = 0; s < 6; ++s) {
        int g = tid + s * 256;
        int n = g / 24, k8 = g - n * 24;
        *(frag8*)&sW1[n * W1_PAD + k8 * 8] = *(const frag8*)(Wm1T + n * 192 + k8 * 8);
    }
#pragma unroll
    for (int s = 0; s < 2; ++s) {
        int g = tid + s * 256;
        int n = g >> 3, k8 = g & 7;
        *(frag8*)&sW2[n * W2_PAD + k8 * 8] = *(const frag8*)(Wm2T + n * 64 + k8 * 8);
    }
    int m0 = m_base + c16;
    int arow = (m0 < M) ? m0 : (M - 1);
    __syncthreads();

    f32x4 acc1[4];
#pragma unroll
    for (int t = 0; t < 4; ++t) acc1[t] = (f32x4)0.f;
    for (int k0 = 0; k0 < 192; k0 += 32) {
        frag8 a = *(const frag8*)(xbf + (size_t)arow * HDIM + k0 + quad * 8);
#pragma unroll
        for (int t = 0; t < 4; ++t) {
            frag8 b = *(const frag8*)&sW1[(t * 16 + c16) * W1_PAD + k0 + quad * 8];
            acc1[t] = __builtin_amdgcn_mfma_f32_16x16x32_bf16(a, b, acc1[t], 0, 0, 0);
        }
    }
#pragma unroll
    for (int t = 0; t < 4; ++t) {
        float bv = b2f(bm1[t * 16 + c16]);
#pragma unroll
        for (int rr = 0; rr < 4; ++rr) {
            float v = fmaxf(acc1[t][rr] + bv, 0.f);
            sH[(w * 16 + quad * 4 + rr) * H_PAD + t * 16 + c16] = f2b(v);
        }
    }
    __syncthreads();

    f32x4 acc2[4];
#pragma unroll
    for (int t = 0; t < 4; ++t) acc2[t] = (f32x4)0.f;
#pragma unroll
    for (int k0 = 0; k0 < 64; k0 += 32) {
        frag8 a = *(const frag8*)&sH[(w * 16 + c16) * H_PAD + k0 + quad * 8];
#pragma unroll
        for (int t = 0; t < 4; ++t) {
            frag8 b = *(const frag8*)&sW2[(t * 16 + c16) * W2_PAD + k0 + quad * 8];
            acc2[t] = __builtin_amdgcn_mfma_f32_16x16x32_bf16(a, b, acc2[t], 0, 0, 0);
        }
    }
#pragma unroll
    for (int t = 0; t < 4; ++t) {
        int col = t * 16 + c16;
        float bv = b2f(bm2[col]);
#pragma unroll
        for (int rr = 0; rr < 4; ++rr) {
            int m = m_base + quad * 4 + rr;
            if (m < M) {
                float v = acc2[t][rr] + bv;
                if (c32) ((float*)out)[(size_t)m * 64 + col] = v;
                else ((__hip_bfloat16*)out)[(size_t)m * 64 + col] = __float2bfloat16(v);
            }
        }
    }
}

// ---------------- fused online-softmax + aggregation: ONE WAVE PER NODE, no barriers ---
// Block 256 = 4 independent waves; wave-private LDS slice; flash-style running (m,s).
// Gather: lanes 0..47 own 4 dims each; 4-unrolled independent u32x2 loads.
__global__ __launch_bounds__(256) void k_agg_sm(
    const u16* __restrict__ feat, const float* __restrict__ el, const float* __restrict__ er,
    const int* __restrict__ src_perm, const int* __restrict__ indptr,
    const u16* __restrict__ bias, u16* __restrict__ outb, int n_nodes) {
    __shared__ int ssrc_s[4][CHUNK];
    __shared__ float salpha_s[4][CHUNK * HEADS_H];
    const int wave = threadIdx.x >> 6, lane = threadIdx.x & 63;
    const int n = blockIdx.x * 4 + wave;
    if (n >= n_nodes) return;
    int* ssrc = ssrc_s[wave];
    float* salpha = salpha_s[wave];
    const int beg = indptr[n];
    const int lenT = indptr[n + 1] - beg;
    const float er0 = er[n * 3 + 0], er1 = er[n * 3 + 1], er2 = er[n * 3 + 2];
    const int u = lane;        // gather lanes: u<48 -> dims [4u,4u+4)
    const int h = u >> 4;
    const u16* fbase = feat + 4 * u;

    float m0 = -INFINITY, m1 = -INFINITY, m2 = -INFINITY;
    float s0 = 0.f, s1 = 0.f, s2 = 0.f;
    float a0 = 0.f, a1 = 0.f, a2 = 0.f, a3 = 0.f;

    for (int c0 = 0; c0 < lenT; c0 += CHUNK) {
        const int len = min(CHUNK, lenT - c0);
        // pass 1: stage src, compute leaky logits, chunk max
        float cm0 = -INFINITY, cm1 = -INFINITY, cm2 = -INFINITY;
        for (int j = lane; j < len; j += 64) {
            int s = src_perm[beg + c0 + j];
            ssrc[j] = s;
            const float* ep = el + (size_t)s * 3;
            float e0 = ep[0] + er0, e1 = ep[1] + er1, e2 = ep[2] + er2;
            e0 = (e0 > 0.f) ? e0 : NEG_SLOPE * e0;
            e1 = (e1 > 0.f) ? e1 : NEG_SLOPE * e1;
            e2 = (e2 > 0.f) ? e2 : NEG_SLOPE * e2;
            salpha[j * 3 + 0] = e0;
            salpha[j * 3 + 1] = e1;
            salpha[j * 3 + 2] = e2;
            cm0 = fmaxf(cm0, e0); cm1 = fmaxf(cm1, e1); cm2 = fmaxf(cm2, e2);
        }
#pragma unroll
        for (int off = 32; off > 0; off >>= 1) {
            cm0 = fmaxf(cm0, __shfl_xor(cm0, off, 64));
            cm1 = fmaxf(cm1, __shfl_xor(cm1, off, 64));
            cm2 = fmaxf(cm2, __shfl_xor(cm2, off, 64));
        }
        float n0 = fmaxf(m0, cm0), n1 = fmaxf(m1, cm1), n2 = fmaxf(m2, cm2);
        float r0 = __expf(m0 - n0), r1 = __expf(m1 - n1), r2 = __expf(m2 - n2);
        __threadfence_block();  // wave-private LDS drain (lgkmcnt)
        // pass 2: exp, chunk sums
        float cs0 = 0.f, cs1 = 0.f, cs2 = 0.f;
        for (int j = lane; j < len; j += 64) {
            float ex0 = __expf(salpha[j * 3 + 0] - n0);
            float ex1 = __expf(salpha[j * 3 + 1] - n1);
            float ex2 = __expf(salpha[j * 3 + 2] - n2);
            salpha[j * 3 + 0] = ex0;
            salpha[j * 3 + 1] = ex1;
            salpha[j * 3 + 2] = ex2;
            cs0 += ex0; cs1 += ex1; cs2 += ex2;
        }
#pragma unroll
        for (int off = 32; off > 0; off >>= 1) {
            cs0 += __shfl_xor(cs0, off, 64);
            cs1 += __shfl_xor(cs1, off, 64);
            cs2 += __shfl_xor(cs2, off, 64);
        }
        s0 = s0 * r0 + cs0; s1 = s1 * r1 + cs1; s2 = s2 * r2 + cs2;
        m0 = n0; m1 = n1; m2 = n2;
        __threadfence_block();
        // gather phase (lanes 0..47), 4 independent loads per group
        if (u < 48) {
            float rh = (h == 0) ? r0 : ((h == 1) ? r1 : r2);
            a0 *= rh; a1 *= rh; a2 *= rh; a3 *= rh;
            for (int j0 = 0; j0 < len; j0 += 4) {
                int jb = min(j0 + 1, len - 1), jc = min(j0 + 2, len - 1), jd = min(j0 + 3, len - 1);
                int sa = ssrc[j0], sb = ssrc[jb], sc = ssrc[jc], sd = ssrc[jd];
                float wa = salpha[j0 * 3 + h];
                float wb = (j0 + 1 < len) ? salpha[jb * 3 + h] : 0.f;
                float wc = (j0 + 2 < len) ? salpha[jc * 3 + h] : 0.f;
                float wd = (j0 + 3 < len) ? salpha[jd * 3 + h] : 0.f;
                u32x2 va = *(const u32x2*)(fbase + (size_t)sa * HDIM);
                u32x2 vb = *(const u32x2*)(fbase + (size_t)sb * HDIM);
                u32x2 vc = *(const u32x2*)(fbase + (size_t)sc * HDIM);
                u32x2 vd = *(const u32x2*)(fbase + (size_t)sd * HDIM);
                a0 += wa * b2f_lo(va.x); a1 += wa * b2f_hi(va.x);
                a2 += wa * b2f_lo(va.y); a3 += wa * b2f_hi(va.y);
                a0 += wb * b2f_lo(vb.x); a1 += wb * b2f_hi(vb.x);
                a2 += wb * b2f_lo(vb.y); a3 += wb * b2f_hi(vb.y);
                a0 += wc * b2f_lo(vc.x); a1 += wc * b2f_hi(vc.x);
                a2 += wc * b2f_lo(vc.y); a3 += wc * b2f_hi(vc.y);
                a0 += wd * b2f_lo(vd.x); a1 += wd * b2f_hi(vd.x);
                a2 += wd * b2f_lo(vd.y); a3 += wd * b2f_hi(vd.y);
            }
        }
    }

    if (u < 48) {
        float shh = (h == 0) ? s0 : ((h == 1) ? s1 : s2);
        float inv = (shh > 0.f) ? 1.f / shh : 0.f;
        u32x2 bv = *(const u32x2*)(bias + 4 * u);
        float v0 = a0 * inv + b2f_lo(bv.x);
        float v1 = a1 * inv + b2f_hi(bv.x);
        float v2 = a2 * inv + b2f_lo(bv.y);
        float v3 = a3 * inv + b2f_hi(bv.y);
        v0 = fmaxf(v0, 0.f); v1 = fmaxf(v1, 0.f);
        v2 = fmaxf(v2, 0.f); v3 = fmaxf(v3, 0.f);
        u32x2 o;
        o.x = (unsigned)f2b(v0) | ((unsigned)f2b(v1) << 16);
        o.y = (unsigned)f2b(v2) | ((unsigned)f2b(v3) << 16);
        *(u32x2*)(outb + (size_t)n * HDIM + 4 * u) = o;
    }
}

// ---------------- launch ----------------
extern "C" void kernel_launch(void* const* d_in, const int* in_sizes, int n_in,
                              void* d_out, int out_size, void* d_ws, size_t ws_size,
                              hipStream_t stream) {
    const void* features = d_in[0];
    const int* src = (const int*)d_in[1];
    const int* dst = (const int*)d_in[2];
    const void* W1 = d_in[3];
    const void* al1 = d_in[4];
    const void* ar1 = d_in[5];
    const void* b1 = d_in[6];
    const void* W2 = d_in[7];
    const void* al2 = d_in[8];
    const void* ar2 = d_in[9];
    const void* b2 = d_in[10];
    const void* Wm1 = d_in[11];
    const void* bm1 = d_in[12];
    const void* Wm2 = d_in[13];
    const void* bm2 = d_in[14];

    char* ws = (char*)d_ws;
    size_t off = 0;
    auto alloc = [&](size_t bytes) -> void* {
        void* p = ws + off;
        off = (off + bytes + 255) & ~(size_t)255;
        return p;
    };
    int* flag = (int*)alloc(4);
    u16* featb = (u16*)alloc((size_t)NN * HDIM * 2);
    u16* xbf = (u16*)alloc((size_t)NN * HDIM * 2);
    float* el = (float*)alloc((size_t)NN * HEADS_H * 4);
    float* er = (float*)alloc((size_t)NN * HEADS_H * 4);
    int* indptr = (int*)alloc((size_t)(NN + 1) * 4);
    int* cnt = (int*)alloc((size_t)NN * 4);
    int* src_perm = (int*)alloc((size_t)NE * 4);
    int* partial = (int*)alloc((size_t)SCAN_NB * 4);
    int* offsets = (int*)alloc((size_t)SCAN_NB * 4);
    u16* W1T = (u16*)alloc((size_t)FIN * HDIM * 2);
    u16* W2T = (u16*)alloc((size_t)HDIM * HDIM * 2);
    u16* Wm1T = (u16*)alloc((size_t)HDIM * 64 * 2);
    u16* Wm2T = (u16*)alloc((size_t)64 * 64 * 2);
    u16* al1c = (u16*)alloc(HDIM * 2);
    u16* ar1c = (u16*)alloc(HDIM * 2);
    u16* b1c = (u16*)alloc(HDIM * 2);
    u16* al2c = (u16*)alloc(HDIM * 2);
    u16* ar2c = (u16*)alloc(HDIM * 2);
    u16* b2c = (u16*)alloc(HDIM * 2);
    u16* bm1c = (u16*)alloc(64 * 2);
    u16* bm2c = (u16*)alloc(64 * 2);

    if (ws_size < off) {
        k_fill_pattern<<<(out_size + 255) / 256, 256, 0, stream>>>((u16*)d_out, out_size, 0x3F80);
        return;
    }

    k_sniff<<<1, 256, 0, stream>>>((const unsigned*)features, flag);

    k_cvt8<<<8, 256, 0, stream>>>(al1, ar1, b1, al2, ar2, b2, bm1, bm2, al1c, ar1c, b1c, al2c,
                                  ar2c, b2c, bm1c, bm2c, flag);
    {
        const int tot = FIN * HDIM + HDIM * HDIM + HDIM * 64 + 64 * 64;
        k_transpose4<<<(tot + 255) / 256, 256, 0, stream>>>(W1, W2, Wm1, Wm2, W1T, W2T, Wm1T,
                                                            Wm2T, flag);
    }

    // CSR by dst
    k_zero<<<(NN + 255) / 256, 256, 0, stream>>>(cnt, NN);
    k_count<<<(NE + 255) / 256, 256, 0, stream>>>(dst, cnt, NE);
    k_scan_partial<<<SCAN_NB, 256, 0, stream>>>(cnt, partial);
    k_scan_mid<<<1, 128, 0, stream>>>(partial, offsets, indptr);
    k_scan_final<<<SCAN_NB, 256, 0, stream>>>(cnt, offsets, indptr);
    k_fill<<<(NE + 255) / 256, 256, 0, stream>>>(dst, src, cnt, src_perm, NE);

    const int g64 = (NN + 63) / 64;   // 782 blocks (GEMM/MLP)
    const int gagg = (NN + 3) / 4;    // 12500 blocks (4 waves = 4 nodes each)

    // GAT layer 1
    k_gemm_lds<<<g64, 256, 0, stream>>>(features, 1, W1T, featb, flag, NN, FIN, el, er, al1c,
                                        ar1c);
    k_agg_sm<<<gagg, 256, 0, stream>>>(featb, el, er, src_perm, indptr, b1c, xbf, NN);

    // GAT layer 2
    k_gemm_lds<<<g64, 256, 0, stream>>>(xbf, 0, W2T, featb, flag, NN, HDIM, el, er, al2c, ar2c);
    k_agg_sm<<<gagg, 256, 0, stream>>>(featb, el, er, src_perm, indptr, b2c, xbf, NN);

    // fused MLP
    k_mlp<<<g64, 256, 0, stream>>>(xbf, Wm1T, Wm2T, bm1c, bm2c, d_out, flag, NN);
}